// Round 6
// baseline (3269.961 us; speedup 1.0000x reference)
//
#include <hip/hip_runtime.h>
#include <hip/hip_bf16.h>
#include <stdint.h>

#define LL 2
#define HH 8
#define EE 512
#define FFD 2048
#define BB 8
#define SS 1024

typedef unsigned short u16;
typedef __attribute__((ext_vector_type(8))) short bf16x8;
typedef __attribute__((ext_vector_type(4))) float f32x4;
typedef __attribute__((ext_vector_type(4))) int int4v;

__device__ __forceinline__ u16 f2bf(float f){
  union { float f; unsigned u; } c; c.f = f;
  unsigned r = (c.u + 0x7FFFu + ((c.u >> 16) & 1u)) >> 16;
  return (u16)r;
}

// ---------------------------------------------------------------------------
// GEMM: C = A(MxK) * B(NxK)^T, bf16 in / f32 accum.
//   A elem addr = AsMHi*(m>>10) + AsMLo*(m&1023) + AsH*(k>>9) + (k&511)
//   B elem addr = BsNHi*(n>>9)  + BsNLo*(n&511)  + BsH*(k>>9) + (k&511)
//   O elem addr = OsMHi*(m>>10) + OsMLo*(m&1023) + OsNHi*(n>>9) + OsNLo*(n&511)
// EP: 0=bf16 out*scale (+causal tile skip), 1=bf16 out+bias, 2=bf16 out
// (+causal K-limit), 3=f32 out+bias+resid, 4=bf16 out+bias+relu
//
// Schedule: BK=32, FOUR K-tile LDS buffers, 3-tile-deep prefetch.
//   prologue: stage tiles 0,1,2 (A,B each; 2 global_load_lds per matrix per
//             wave -> 12 loads in flight)
//   per K-tile t: vmcnt(8|4|0 by tail) retires tile t's 4 loads ->
//                 s_barrier (residency now global) -> stage tile t+3 ->
//                 12 ds_read_b128 -> setprio(1) 32 MFMA setprio(0) ->
//                 lgkmcnt(0) (reads retired before next barrier).
//   Buffer (t+3)&3 was last read at tile t-1, whose reads completed before
//   this barrier -> no WAR race. vmcnt never drains to 0 in steady state.
// Swizzle (64B rows): LDS 16B-slot s holds global k-slot s ^ ((row>>1)&3);
//   pre-applied on the global source, inverted on ds_read -> 2-way bank
//   aliasing only (free, m136). Linear LDS dest for global_load_lds.
// ---------------------------------------------------------------------------
struct GP {
  const u16* A; const u16* B;
  const float* bias; const float* resid;
  void* out;
  long AsMHi, AsMLo, AsH;
  long BsNHi, BsNLo, BsH;
  long Abatch, Bbatch, Obatch;
  long OsMHi, OsMLo, OsNHi, OsNLo;
  int M, N, K, causal;
  float scale;
};

__device__ __forceinline__ int xcd_swz(int bid, int nwg){
  if (nwg < 16) return bid;
  const int q = nwg >> 3, r = nwg & 7;
  const int xcd = bid & 7, loc = bid >> 3;
  return (xcd < r ? xcd * (q + 1) : r * (q + 1) + (xcd - r) * q) + loc;
}

template<int EP, int BIG>
__global__ __launch_bounds__(BIG ? 512 : 256, 2) void k_gemm(GP p){
  constexpr int TM = BIG ? 256 : 128;     // square tile edge
  constexpr int SH = BIG ? 8 : 7;
  constexpr int MI = BIG ? 8 : 4;         // per-wave m-fragments (x4 n-frags)
  const int tilesN = p.N >> SH;
  const int bid = xcd_swz(blockIdx.x, gridDim.x);
  const int m0 = (bid / tilesN) << SH;
  const int n0 = (bid % tilesN) << SH;
  if (EP == 0 && p.causal && n0 > m0) return;   // fully-masked causal tile
  const long bb = blockIdx.y;
  const u16* __restrict__ Ag = p.A + bb * p.Abatch;
  const u16* __restrict__ Bg = p.B + bb * p.Bbatch;

  __shared__ __align__(16) u16 As[4][TM * 32];
  __shared__ __align__(16) u16 Bs[4][TM * 32];

  const int t = threadIdx.x;
  const int lane = t & 63;
  const int wv = t >> 6;
  const int wr = BIG ? ((wv >> 2) << 7) : ((wv >> 1) << 6);
  const int wc = BIG ? ((wv & 3) << 6) : ((wv & 1) << 6);

  // ---- staging geometry: wave wv instr i covers rows wv*32+i*16+(lane>>2),
  //      16B slot (lane&3); source k-slot pre-XORed with (row>>1)&3 = (lane>>3)&3
  long aoff[2], boff[2];
  #pragma unroll
  for (int i = 0; i < 2; ++i){
    const int r = (wv << 5) + (i << 4) + (lane >> 2);
    const int kx = (((lane & 3) ^ ((lane >> 3) & 3)) << 3);
    const int gm = m0 + r;
    aoff[i] = (long)(gm >> 10) * p.AsMHi + (long)(gm & 1023) * p.AsMLo + kx;
    const int gn = n0 + r;
    boff[i] = (long)(gn >> 9) * p.BsNHi + (long)(gn & 511) * p.BsNLo + kx;
  }

  // ---- fragment ds_read byte offsets (row*64 + (slot g=lane>>4 ^ (row>>1)&3)*16)
  int afB[MI], bvB[4];
  const int slotXor = (((lane >> 4) ^ ((lane >> 1) & 3)) << 4);
  #pragma unroll
  for (int mi = 0; mi < MI; ++mi)
    afB[mi] = (wr + (mi << 4) + (lane & 15)) * 64 + slotXor;
  #pragma unroll
  for (int ni = 0; ni < 4; ++ni)
    bvB[ni] = (wc + (ni << 4) + (lane & 15)) * 64 + slotXor;

  int Klim = p.K;
  if (EP == 2 && p.causal) { int kl = m0 + TM; Klim = kl < p.K ? kl : p.K; }
  const int T = Klim >> 5;               // K-tiles of 32 (always >= 8 here)

  f32x4 acc[MI][4];
  #pragma unroll
  for (int a = 0; a < MI; ++a)
    #pragma unroll
    for (int b = 0; b < 4; ++b)
      acc[a][b] = (f32x4){0.f, 0.f, 0.f, 0.f};

  auto stageA = [&](int tt){
    const int k0 = tt << 5;
    const long ka = (long)(k0 >> 9) * p.AsH + (k0 & 511);
    u16* dst = &As[tt & 3][wv << 10];
    #pragma unroll
    for (int i = 0; i < 2; ++i)
      __builtin_amdgcn_global_load_lds(
        (const __attribute__((address_space(1))) void*)(Ag + aoff[i] + ka),
        (__attribute__((address_space(3))) void*)(dst + (i << 9)), 16, 0, 0);
  };
  auto stageB = [&](int tt){
    const int k0 = tt << 5;
    const long kb = (long)(k0 >> 9) * p.BsH + (k0 & 511);
    u16* dst = &Bs[tt & 3][wv << 10];
    #pragma unroll
    for (int i = 0; i < 2; ++i)
      __builtin_amdgcn_global_load_lds(
        (const __attribute__((address_space(1))) void*)(Bg + boff[i] + kb),
        (__attribute__((address_space(3))) void*)(dst + (i << 9)), 16, 0, 0);
  };

  // prologue: tiles 0,1,2 in flight (12 loads per wave)
  stageA(0); stageB(0); stageA(1); stageB(1); stageA(2); stageB(2);

  for (int tt = 0; tt < T; ++tt){
    const int ahead = T - 1 - tt;
    if (ahead >= 2)      asm volatile("s_waitcnt vmcnt(8)" ::: "memory");
    else if (ahead == 1) asm volatile("s_waitcnt vmcnt(4)" ::: "memory");
    else                 asm volatile("s_waitcnt vmcnt(0)" ::: "memory");
    __builtin_amdgcn_s_barrier();        // tile tt resident for all waves
    if (tt + 3 < T){ stageA(tt + 3); stageB(tt + 3); }

    const char* AsB = (const char*)As[tt & 3];
    const char* BsB = (const char*)Bs[tt & 3];
    bf16x8 af[MI], bv[4];
    #pragma unroll
    for (int mi = 0; mi < MI; ++mi)
      af[mi] = *reinterpret_cast<const bf16x8*>(AsB + afB[mi]);
    #pragma unroll
    for (int ni = 0; ni < 4; ++ni)
      bv[ni] = *reinterpret_cast<const bf16x8*>(BsB + bvB[ni]);

    __builtin_amdgcn_s_setprio(1);
    #pragma unroll
    for (int mi = 0; mi < MI; ++mi)
      #pragma unroll
      for (int ni = 0; ni < 4; ++ni)
        acc[mi][ni] = __builtin_amdgcn_mfma_f32_16x16x32_bf16(af[mi], bv[ni], acc[mi][ni], 0, 0, 0);
    __builtin_amdgcn_s_setprio(0);
    asm volatile("s_waitcnt lgkmcnt(0)" ::: "memory");  // reads retired pre-barrier
  }

  // epilogue: D row=(lane>>4)*4+i, col=lane&15
  const int cm = (lane >> 4) << 2;
  const int cn = lane & 15;
  float biasv[4];
  if (EP == 1 || EP == 3 || EP == 4){
    #pragma unroll
    for (int ni = 0; ni < 4; ++ni)
      biasv[ni] = p.bias[n0 + wc + (ni << 4) + cn];
  }
  #pragma unroll
  for (int mi = 0; mi < MI; ++mi){
    #pragma unroll
    for (int i = 0; i < 4; ++i){
      const int m = m0 + wr + (mi << 4) + cm + i;
      const long ob = bb * p.Obatch + (long)(m >> 10) * p.OsMHi + (long)(m & 1023) * p.OsMLo;
      #pragma unroll
      for (int ni = 0; ni < 4; ++ni){
        const int n = n0 + wc + (ni << 4) + cn;
        const long oa = ob + (long)(n >> 9) * p.OsNHi + (long)(n & 511) * p.OsNLo;
        float v = acc[mi][ni][i];
        if (EP == 0) ((u16*)p.out)[oa] = f2bf(v * p.scale);
        else if (EP == 1) ((u16*)p.out)[oa] = f2bf(v + biasv[ni]);
        else if (EP == 2) ((u16*)p.out)[oa] = f2bf(v);
        else if (EP == 3) ((float*)p.out)[oa] = v + biasv[ni] + p.resid[oa];
        else { float r = v + biasv[ni]; ((u16*)p.out)[oa] = f2bf(r > 0.f ? r : 0.f); }
      }
    }
  }
}

// ---------------------------------------------------------------------------
__global__ void k_cvt(const float* __restrict__ s, u16* __restrict__ d, int n){
  const int i = (blockIdx.x * 256 + threadIdx.x) << 3;
  if (i >= n) return;
  f32x4 a = *reinterpret_cast<const f32x4*>(s + i);
  f32x4 b = *reinterpret_cast<const f32x4*>(s + i + 4);
  union { u16 us[8]; int4v v; } u;
  #pragma unroll
  for (int j = 0; j < 4; ++j){ u.us[j] = f2bf(a[j]); u.us[4 + j] = f2bf(b[j]); }
  *reinterpret_cast<int4v*>(d + i) = u.v;
}

__global__ void k_init(const float* __restrict__ x, float* __restrict__ xf,
                       u16* __restrict__ xb, int n){
  const int i = (blockIdx.x * 256 + threadIdx.x) << 3;
  if (i >= n) return;
  f32x4 a = *reinterpret_cast<const f32x4*>(x + i);
  f32x4 b = *reinterpret_cast<const f32x4*>(x + i + 4);
  *reinterpret_cast<f32x4*>(xf + i) = a;
  *reinterpret_cast<f32x4*>(xf + i + 4) = b;
  union { u16 us[8]; int4v v; } u;
  #pragma unroll
  for (int j = 0; j < 4; ++j){ u.us[j] = f2bf(a[j]); u.us[4 + j] = f2bf(b[j]); }
  *reinterpret_cast<int4v*>(xb + i) = u.v;
}

// in-place row softmax over bf16 scores[0..q]; zero beyond q; P *= alpha[h]
__global__ __launch_bounds__(128) void k_softmax(u16* __restrict__ sp,
                                                 const float* __restrict__ alphas,
                                                 int pbase){
  const long row = blockIdx.x;
  const int q = (int)(row & (SS - 1));
  const int h = (pbase + (int)(row >> 10)) & (HH - 1);
  u16* rp = sp + row * SS;
  const int t = threadIdx.x;
  const int i0 = t << 3;
  bf16x8 rv = *reinterpret_cast<const bf16x8*>(rp + i0);
  float v[8];
  float lm = -1e30f;
  #pragma unroll
  for (int j = 0; j < 8; ++j){
    union { unsigned u; float f; } c; c.u = ((unsigned)(u16)rv[j]) << 16;
    v[j] = (i0 + j <= q) ? c.f : -1e30f;
    lm = fmaxf(lm, v[j]);
  }
  #pragma unroll
  for (int o = 32; o; o >>= 1) lm = fmaxf(lm, __shfl_xor(lm, o));
  __shared__ float red[2];
  if ((t & 63) == 0) red[t >> 6] = lm;
  __syncthreads();
  const float m = fmaxf(red[0], red[1]);
  float ls = 0.f;
  #pragma unroll
  for (int j = 0; j < 8; ++j){
    float e = exp2f((v[j] - m) * 1.4426950408889634f);
    e = (i0 + j <= q) ? e : 0.f;
    v[j] = e; ls += e;
  }
  #pragma unroll
  for (int o = 32; o; o >>= 1) ls += __shfl_xor(ls, o);
  __syncthreads();
  if ((t & 63) == 0) red[t >> 6] = ls;
  __syncthreads();
  const float inv = alphas[h] / (red[0] + red[1]);
  union { u16 us[8]; bf16x8 v8; } o8;
  #pragma unroll
  for (int j = 0; j < 8; ++j) o8.us[j] = f2bf(v[j] * inv);
  *reinterpret_cast<bf16x8*>(rp + i0) = o8.v8;
}

// per-pair (S,E) -> (E,S), 64x64 bf16 tiles; blockIdx.y = local pair
__global__ __launch_bounds__(256) void k_transpose(const u16* __restrict__ v,
                                                   u16* __restrict__ vt){
  const long bh = blockIdx.y;
  const int ts = blockIdx.x >> 3;
  const int td = blockIdx.x & 7;
  const u16* src = v + bh * (long)(SS * EE) + (long)(ts * 64) * EE + td * 64;
  u16* dst = vt + bh * (long)(SS * EE) + (long)(td * 64) * SS + ts * 64;
  __shared__ __align__(16) u16 tl[64][80];
  const int t = threadIdx.x;
  #pragma unroll
  for (int it = 0; it < 2; ++it){
    int id = t + it * 256;
    int r = id >> 3, c = (id & 7) << 3;
    *reinterpret_cast<int4v*>(&tl[r][c]) =
        *reinterpret_cast<const int4v*>(src + (long)r * EE + c);
  }
  __syncthreads();
  #pragma unroll
  for (int it = 0; it < 2; ++it){
    int id = t + it * 256;
    int r = id >> 3, c = (id & 7) << 3;
    union { u16 us[8]; int4v v; } u;
    #pragma unroll
    for (int j = 0; j < 8; ++j) u.us[j] = tl[c + j][r];
    *reinterpret_cast<int4v*>(dst + (long)r * SS + c) = u.v;
  }
}

__global__ __launch_bounds__(256) void k_ln(const float* __restrict__ src,
                                            const float* __restrict__ g,
                                            const float* __restrict__ b,
                                            float* __restrict__ fdst,
                                            u16* __restrict__ bdst){
  const long row = blockIdx.x;
  const float* x = src + row * EE;
  const int t = threadIdx.x;
  float v0 = x[t], v1 = x[t + 256];
  float s = v0 + v1;
  for (int o = 32; o; o >>= 1) s += __shfl_xor(s, o);
  __shared__ float red[4];
  if ((t & 63) == 0) red[t >> 6] = s;
  __syncthreads();
  const float mean = (red[0] + red[1] + red[2] + red[3]) * (1.0f / EE);
  float d0 = v0 - mean, d1 = v1 - mean;
  float vs = d0 * d0 + d1 * d1;
  for (int o = 32; o; o >>= 1) vs += __shfl_xor(vs, o);
  __syncthreads();
  if ((t & 63) == 0) red[t >> 6] = vs;
  __syncthreads();
  const float var = (red[0] + red[1] + red[2] + red[3]) * (1.0f / EE);
  const float rstd = rsqrtf(var + 1e-5f);
  float o0 = d0 * rstd * g[t] + b[t];
  float o1 = d1 * rstd * g[t + 256] + b[t + 256];
  fdst[row * EE + t] = o0;
  fdst[row * EE + t + 256] = o1;
  bdst[row * EE + t] = f2bf(o0);
  bdst[row * EE + t + 256] = f2bf(o1);
}

__global__ void k_sumbo(const float* __restrict__ bo, float* __restrict__ dst){
  const int o = blockIdx.x * 256 + threadIdx.x;
  if (o >= EE) return;
  float s = 0.f;
  #pragma unroll
  for (int h = 0; h < HH; ++h) s += bo[h * EE + o];
  dst[o] = s;
}

// ---------------------------------------------------------------------------
static inline void gemm_launch(int EP, const GP& p, int batch, hipStream_t st){
  dim3 g((unsigned)((p.M >> 7) * (p.N >> 7)), (unsigned)batch);
  switch (EP){
    case 0: k_gemm<0,0><<<g, 256, 0, st>>>(p); break;
    case 1: k_gemm<1,0><<<g, 256, 0, st>>>(p); break;
    case 2: k_gemm<2,0><<<g, 256, 0, st>>>(p); break;
    case 3: k_gemm<3,0><<<g, 256, 0, st>>>(p); break;
    case 4: k_gemm<4,0><<<g, 256, 0, st>>>(p); break;
  }
}

static inline void gemm_launch256(int EP, const GP& p, int batch, hipStream_t st){
  dim3 g((unsigned)((p.M >> 8) * (p.N >> 8)), (unsigned)batch);
  switch (EP){
    case 0: k_gemm<0,1><<<g, 512, 0, st>>>(p); break;
    case 1: k_gemm<1,1><<<g, 512, 0, st>>>(p); break;
    case 2: k_gemm<2,1><<<g, 512, 0, st>>>(p); break;
    case 3: k_gemm<3,1><<<g, 512, 0, st>>>(p); break;
    case 4: k_gemm<4,1><<<g, 512, 0, st>>>(p); break;
  }
}

extern "C" void kernel_launch(void* const* d_in, const int* in_sizes, int n_in,
                              void* d_out, int out_size, void* d_ws, size_t ws_size,
                              hipStream_t stream){
  const float* x    = (const float*)d_in[0];
  const float* Wq   = (const float*)d_in[1];
  const float* bq   = (const float*)d_in[2];
  const float* Wk   = (const float*)d_in[3];
  const float* bk   = (const float*)d_in[4];
  const float* Wv   = (const float*)d_in[5];
  const float* bv   = (const float*)d_in[6];
  const float* Wo   = (const float*)d_in[7];
  const float* bo   = (const float*)d_in[8];
  const float* alph = (const float*)d_in[9];
  const float* ln1g = (const float*)d_in[10];
  const float* ln1b = (const float*)d_in[11];
  const float* W1   = (const float*)d_in[12];
  const float* b1   = (const float*)d_in[13];
  const float* W2   = (const float*)d_in[14];
  const float* b2   = (const float*)d_in[15];
  const float* ln2g = (const float*)d_in[16];
  const float* ln2b = (const float*)d_in[17];
  float* out = (float*)d_out;

  const size_t nWh = (size_t)HH * EE * EE;
  const size_t nWf = (size_t)FFD * EE;
  const size_t nX  = (size_t)BB * SS * EE;
  const size_t nQ  = (size_t)BB * HH * SS * EE;
  const size_t nPairV  = (size_t)SS * EE;
  const size_t nPairS  = (size_t)SS * SS;

  const size_t fixedB = 2*nWh*4 + 2*nWf*2
                      + 4*nX + 2*nX
                      + 3 * 2*nQ
                      + 4096 + 32*256;
  const size_t perPairB = 2*nPairS + 2*nPairV;
  int CH = 64;
  while (CH > 1 && fixedB + (size_t)CH * perPairB > ws_size) CH >>= 1;
  const int NC = 64 / CH;

  char* w = (char*)d_ws;
  size_t off = 0;
  auto take = [&](size_t bytes) -> char* {
    char* p = w + off;
    off += (bytes + 255) & ~(size_t)255;
    return p;
  };

  u16* wqb = (u16*)take(2 * nWh);
  u16* wkb = (u16*)take(2 * nWh);
  u16* wvb = (u16*)take(2 * nWh);
  u16* wob = (u16*)take(2 * nWh);
  u16* w1b = (u16*)take(2 * nWf);
  u16* w2b = (u16*)take(2 * nWf);
  float* xf = (float*)take(4 * nX);
  u16* xb   = (u16*)take(2 * nX);
  u16* qb   = (u16*)take(2 * nQ);
  u16* kb   = (u16*)take(2 * nQ);
  u16* vb   = (u16*)take(2 * nQ);
  float* bo_sum = (float*)take(4 * EE);
  u16* vtb  = (u16*)take(2 * nPairV * CH);
  u16* sc   = (u16*)take(2 * nPairS * CH);
  float* tmp = out;
  u16* hid = qb;

  auto cvt = [&](const float* s, u16* d, size_t n){
    k_cvt<<<dim3((unsigned)(n / 2048)), 256, 0, stream>>>(s, d, (int)n);
  };
  k_init<<<dim3((unsigned)(nX / 2048)), 256, 0, stream>>>(x, xf, xb, (int)nX);

  for (int i = 0; i < LL; ++i){
    cvt(Wq + i * nWh, wqb, nWh); cvt(Wk + i * nWh, wkb, nWh);
    cvt(Wv + i * nWh, wvb, nWh); cvt(Wo + i * nWh, wob, nWh);
    cvt(W1 + i * nWf, w1b, nWf); cvt(W2 + i * nWf, w2b, nWf);

    // ---- QKV projections (256-tile, deep pipeline) ----
    GP p{};
    p.AsMHi = (long)1024 * EE; p.AsMLo = EE; p.AsH = 0;
    p.BsNHi = (long)EE * EE;   p.BsNLo = EE; p.BsH = 0;
    p.Abatch = p.Bbatch = p.Obatch = 0;
    p.OsMHi = (long)HH * SS * EE; p.OsMLo = EE; p.OsNHi = (long)SS * EE; p.OsNLo = 1;
    p.M = BB * SS; p.N = HH * EE; p.K = EE;
    p.A = xb; p.scale = 1.f; p.causal = 0; p.resid = nullptr;
    p.B = wqb; p.bias = bq + (size_t)i * HH * EE; p.out = qb;
    gemm_launch256(1, p, 1, stream);
    p.B = wkb; p.bias = bk + (size_t)i * HH * EE; p.out = kb;
    gemm_launch256(1, p, 1, stream);
    p.B = wvb; p.bias = bv + (size_t)i * HH * EE; p.out = vb;
    gemm_launch256(1, p, 1, stream);

    // ---- attention, chunked over (b,h) pairs ----
    for (int c = 0; c < NC; ++c){
      const size_t pbase = (size_t)c * CH;
      const size_t poff = pbase * nPairV;

      k_transpose<<<dim3(128, CH), 256, 0, stream>>>(vb + poff, vtb);

      GP ps{};
      ps.A = qb + poff; ps.B = kb + poff; ps.out = sc;
      ps.AsMHi = 0; ps.AsMLo = EE; ps.AsH = 0;
      ps.BsNHi = (long)512 * EE; ps.BsNLo = EE; ps.BsH = 0;
      ps.Abatch = (long)SS * EE; ps.Bbatch = (long)SS * EE; ps.Obatch = (long)SS * SS;
      ps.OsMHi = 0; ps.OsMLo = SS; ps.OsNHi = 512; ps.OsNLo = 1;
      ps.M = SS; ps.N = SS; ps.K = EE;
      ps.scale = 0.044194173824159216f; ps.causal = 1;
      ps.bias = nullptr; ps.resid = nullptr;
      gemm_launch256(0, ps, CH, stream);

      k_softmax<<<dim3(CH * SS), 128, 0, stream>>>(sc, alph, (int)pbase);

      GP pv{};
      pv.A = sc; pv.B = vtb; pv.out = vb + poff;
      pv.AsMHi = 0; pv.AsMLo = SS; pv.AsH = 512;
      pv.BsNHi = 0; pv.BsNLo = SS; pv.BsH = 512;
      pv.Abatch = (long)SS * SS; pv.Bbatch = (long)EE * SS; pv.Obatch = (long)SS * EE;
      pv.OsMHi = 0; pv.OsMLo = EE; pv.OsNHi = 0; pv.OsNLo = 1;
      pv.M = SS; pv.N = EE; pv.K = SS; pv.causal = 1;
      pv.scale = 1.f; pv.bias = nullptr; pv.resid = nullptr;
      gemm_launch256(2, pv, CH, stream);
    }

    k_sumbo<<<dim3(2), 256, 0, stream>>>(bo + (size_t)i * HH * EE, bo_sum);

    // ---- attn_out = ao @ Wo^T + bias + resid (128-tile, K=4096) ----
    GP pw{};
    pw.A = vb; pw.B = wob; pw.out = tmp;
    pw.AsMHi = (long)HH * SS * EE; pw.AsMLo = EE; pw.AsH = (long)SS * EE;
    pw.BsNHi = 0; pw.BsNLo = EE; pw.BsH = (long)EE * EE;
    pw.Abatch = pw.Bbatch = pw.Obatch = 0;
    pw.OsMHi = (long)SS * EE; pw.OsMLo = EE; pw.OsNHi = 0; pw.OsNLo = 1;
    pw.M = BB * SS; pw.N = EE; pw.K = HH * EE;
    pw.bias = bo_sum; pw.resid = xf; pw.scale = 1.f; pw.causal = 0;
    gemm_launch(3, pw, 1, stream);

    k_ln<<<dim3(BB * SS), 256, 0, stream>>>(tmp, ln1g + (size_t)i * EE,
                                            ln1b + (size_t)i * EE, xf, xb);

    // ---- FFN up (256-tile) ----
    GP p1{};
    p1.A = xb; p1.B = w1b; p1.out = hid;
    p1.AsMHi = (long)1024 * EE; p1.AsMLo = EE; p1.AsH = 0;
    p1.BsNHi = (long)512 * EE; p1.BsNLo = EE; p1.BsH = 0;
    p1.Abatch = p1.Bbatch = p1.Obatch = 0;
    p1.OsMHi = (long)1024 * FFD; p1.OsMLo = FFD; p1.OsNHi = 512; p1.OsNLo = 1;
    p1.M = BB * SS; p1.N = FFD; p1.K = EE;
    p1.bias = b1 + (size_t)i * FFD; p1.resid = nullptr; p1.scale = 1.f; p1.causal = 0;
    gemm_launch256(4, p1, 1, stream);

    // ---- FFN down (128-tile, K=2048) ----
    GP p2{};
    p2.A = hid; p2.B = w2b; p2.out = tmp;
    p2.AsMHi = (long)1024 * FFD; p2.AsMLo = FFD; p2.AsH = 512;
    p2.BsNHi = 0; p2.BsNLo = FFD; p2.BsH = 512;
    p2.Abatch = p2.Bbatch = p2.Obatch = 0;
    p2.OsMHi = (long)SS * EE; p2.OsMLo = EE; p2.OsNHi = 0; p2.OsNLo = 1;
    p2.M = BB * SS; p2.N = EE; p2.K = FFD;
    p2.bias = b2 + (size_t)i * EE; p2.resid = xf; p2.scale = 1.f; p2.causal = 0;
    gemm_launch(3, p2, 1, stream);

    float* fdst = (i == LL - 1) ? out : xf;
    k_ln<<<dim3(BB * SS), 256, 0, stream>>>(tmp, ln2g + (size_t)i * EE,
                                            ln2b + (size_t)i * EE, fdst, xb);
  }
}

// Round 8
// 2058.744 us; speedup vs baseline: 1.5883x; 1.5883x over previous
//
#include <hip/hip_runtime.h>
#include <hip/hip_bf16.h>
#include <stdint.h>

#define LL 2
#define HH 8
#define EE 512
#define FFD 2048
#define BB 8
#define SS 1024

typedef unsigned short u16;
typedef __attribute__((ext_vector_type(8))) short bf16x8;
typedef __attribute__((ext_vector_type(4))) float f32x4;
typedef __attribute__((ext_vector_type(4))) int int4v;

__device__ __forceinline__ u16 f2bf(float f){
  union { float f; unsigned u; } c; c.f = f;
  unsigned r = (c.u + 0x7FFFu + ((c.u >> 16) & 1u)) >> 16;
  return (u16)r;
}

// ---------------------------------------------------------------------------
// 128x128 tile GEMM, C = A(MxK) * B(NxK)^T, bf16 in / f32 accum.
// Round-2-best schedule (measured fastest): single 32KB LDS, __syncthreads
// pair per K-step, global_load_lds width=16, linear LDS dest, pre-swizzled
// global source, swizzled ds_read. No inline asm (m141 lesson).
//   A elem addr = AsMHi*(m>>10) + AsMLo*(m&1023) + AsH*(k>>9) + (k&511)
//   B elem addr = BsNHi*(n>>9)  + BsNLo*(n&511)  + BsH*(k>>9) + (k&511)
//   O elem addr = OsMHi*(m>>10) + OsMLo*(m&1023) + OsNHi*(n>>9) + OsNLo*(n&511)
// EP: 0=bf16 out*scale (+causal tile skip), 1=bf16 out+bias, 2=bf16 out
// (+causal K-limit), 4=bf16 out+bias+relu, 5=f32 raw partial (split-K:
// blockIdx.y = part, K range [part*Kpart, +Kpart), out += part*Obatch)
// ---------------------------------------------------------------------------
struct GP {
  const u16* A; const u16* B;
  const float* bias; const float* resid;
  void* out;
  long AsMHi, AsMLo, AsH;
  long BsNHi, BsNLo, BsH;
  long Abatch, Bbatch, Obatch;
  long OsMHi, OsMLo, OsNHi, OsNLo;
  int M, N, K, causal, Kpart;
  float scale;
};

__device__ __forceinline__ int xcd_swz(int bid, int nwg){
  if (nwg < 16) return bid;
  const int q = nwg >> 3, r = nwg & 7;
  const int xcd = bid & 7, loc = bid >> 3;
  return (xcd < r ? xcd * (q + 1) : r * (q + 1) + (xcd - r) * q) + loc;
}

template<int EP>
__global__ __launch_bounds__(256, 3) void k_gemm(GP p){
  const int tilesN = p.N >> 7;
  const int bid = xcd_swz(blockIdx.x, gridDim.x);
  const int m0 = (bid / tilesN) << 7;
  const int n0 = (bid % tilesN) << 7;
  if (EP == 0 && p.causal && n0 > m0) return;   // fully-masked causal tile
  const long bb = blockIdx.y;
  const u16* __restrict__ Ag = p.A + bb * p.Abatch;
  const u16* __restrict__ Bg = p.B + bb * p.Bbatch;

  __shared__ __align__(16) u16 As[128 * 64];
  __shared__ __align__(16) u16 Bs[128 * 64];
  char* AsB = (char*)As;
  char* BsB = (char*)Bs;

  const int t = threadIdx.x;
  const int lane = t & 63;
  const int wv = t >> 6;
  const int wr = (wv >> 1) << 6;   // wave row origin (0/64)
  const int wc = (wv & 1) << 6;    // wave col origin (0/64)

  // staging geometry: wave wv, instr j -> LDS rows (wv*4+j)*8 .. +8
  // lane -> row +(lane>>3), 16B slot (lane&7). Global k pre-XORed so that
  // LDS byte c of row r holds global slab byte c ^ ((r&7)<<4).
  long aoff[4], boff[4];
  #pragma unroll
  for (int j = 0; j < 4; ++j){
    const int r = ((wv << 2) + j) * 8 + (lane >> 3);
    const int kx = ((lane & 7) << 3) ^ ((r & 7) << 3);
    const int gm = m0 + r;
    aoff[j] = (long)(gm >> 10) * p.AsMHi + (long)(gm & 1023) * p.AsMLo + kx;
    const int gn = n0 + r;
    boff[j] = (long)(gn >> 9) * p.BsNHi + (long)(gn & 511) * p.BsNLo + kx;
  }

  int kBeg = 0;
  int Klim = p.K;
  if (EP == 2 && p.causal) { int kl = m0 + 128; Klim = kl < p.K ? kl : p.K; }
  if (EP == 5) { kBeg = (int)bb * p.Kpart; Klim = kBeg + p.Kpart; }

  f32x4 acc[4][4];
  #pragma unroll
  for (int a = 0; a < 4; ++a)
    #pragma unroll
    for (int b = 0; b < 4; ++b)
      acc[a][b] = (f32x4){0.f, 0.f, 0.f, 0.f};

  for (int k0 = kBeg; k0 < Klim; k0 += 64){
    const long ka = (long)(k0 >> 9) * p.AsH + (k0 & 511);
    const long kb = (long)(k0 >> 9) * p.BsH + (k0 & 511);
    __syncthreads();   // LDS free (previous MFMA phase done)
    #pragma unroll
    for (int j = 0; j < 4; ++j){
      const int ldsOff = (((wv << 2) + j) << 9);   // u16 elems, 1KB per instr
      __builtin_amdgcn_global_load_lds(
          (const __attribute__((address_space(1))) void*)(Ag + aoff[j] + ka),
          (__attribute__((address_space(3))) void*)(As + ldsOff), 16, 0, 0);
      __builtin_amdgcn_global_load_lds(
          (const __attribute__((address_space(1))) void*)(Bg + boff[j] + kb),
          (__attribute__((address_space(3))) void*)(Bs + ldsOff), 16, 0, 0);
    }
    __syncthreads();   // tile resident
    #pragma unroll
    for (int kk = 0; kk < 2; ++kk){
      bf16x8 af[4], bv[4];
      #pragma unroll
      for (int mi = 0; mi < 4; ++mi){
        int row = wr + (mi << 4) + (lane & 15);
        int bc = ((kk << 6) + ((lane >> 4) << 4)) ^ ((row & 7) << 4);
        af[mi] = *reinterpret_cast<const bf16x8*>(AsB + row * 128 + bc);
      }
      #pragma unroll
      for (int ni = 0; ni < 4; ++ni){
        int row = wc + (ni << 4) + (lane & 15);
        int bc = ((kk << 6) + ((lane >> 4) << 4)) ^ ((row & 7) << 4);
        bv[ni] = *reinterpret_cast<const bf16x8*>(BsB + row * 128 + bc);
      }
      #pragma unroll
      for (int mi = 0; mi < 4; ++mi)
        #pragma unroll
        for (int ni = 0; ni < 4; ++ni)
          acc[mi][ni] = __builtin_amdgcn_mfma_f32_16x16x32_bf16(af[mi], bv[ni], acc[mi][ni], 0, 0, 0);
    }
  }

  // epilogue: D row=(lane>>4)*4+i, col=lane&15
  const int cm = (lane >> 4) << 2;
  const int cn = lane & 15;
  float biasv[4];
  if (EP == 1 || EP == 4){
    #pragma unroll
    for (int ni = 0; ni < 4; ++ni)
      biasv[ni] = p.bias[n0 + wc + (ni << 4) + cn];
  }
  #pragma unroll
  for (int mi = 0; mi < 4; ++mi){
    #pragma unroll
    for (int i = 0; i < 4; ++i){
      const int m = m0 + wr + (mi << 4) + cm + i;
      const long ob = bb * p.Obatch + (long)(m >> 10) * p.OsMHi + (long)(m & 1023) * p.OsMLo;
      #pragma unroll
      for (int ni = 0; ni < 4; ++ni){
        const int n = n0 + wc + (ni << 4) + cn;
        const long oa = ob + (long)(n >> 9) * p.OsNHi + (long)(n & 511) * p.OsNLo;
        float v = acc[mi][ni][i];
        if (EP == 0) ((u16*)p.out)[oa] = f2bf(v * p.scale);
        else if (EP == 1) ((u16*)p.out)[oa] = f2bf(v + biasv[ni]);
        else if (EP == 2) ((u16*)p.out)[oa] = f2bf(v);
        else if (EP == 5) ((float*)p.out)[oa] = v;
        else { float r = v + biasv[ni]; ((u16*)p.out)[oa] = f2bf(r > 0.f ? r : 0.f); }
      }
    }
  }
}

// ---------------------------------------------------------------------------
// out[i] = sum_{p<4} part[p][i] + bias[i&511] + resid[i]   (f32, vec4)
__global__ __launch_bounds__(256) void k_red4(const float* __restrict__ part,
                                              const float* __restrict__ bias,
                                              const float* __restrict__ resid,
                                              float* __restrict__ out, int mn){
  const int i = (blockIdx.x * 256 + threadIdx.x) << 2;
  if (i >= mn) return;
  f32x4 s = *reinterpret_cast<const f32x4*>(part + i);
  #pragma unroll
  for (int q = 1; q < 4; ++q){
    f32x4 v = *reinterpret_cast<const f32x4*>(part + (size_t)q * mn + i);
    s.x += v.x; s.y += v.y; s.z += v.z; s.w += v.w;
  }
  f32x4 b = *reinterpret_cast<const f32x4*>(bias + (i & 511));
  f32x4 r = *reinterpret_cast<const f32x4*>(resid + i);
  s.x += b.x + r.x; s.y += b.y + r.y; s.z += b.z + r.z; s.w += b.w + r.w;
  *reinterpret_cast<f32x4*>(out + i) = s;
}

// ---------------------------------------------------------------------------
__global__ void k_cvt(const float* __restrict__ s, u16* __restrict__ d, int n){
  const int i = (blockIdx.x * 256 + threadIdx.x) << 3;
  if (i >= n) return;
  f32x4 a = *reinterpret_cast<const f32x4*>(s + i);
  f32x4 b = *reinterpret_cast<const f32x4*>(s + i + 4);
  union { u16 us[8]; int4v v; } u;
  #pragma unroll
  for (int j = 0; j < 4; ++j){ u.us[j] = f2bf(a[j]); u.us[4 + j] = f2bf(b[j]); }
  *reinterpret_cast<int4v*>(d + i) = u.v;
}

__global__ void k_init(const float* __restrict__ x, float* __restrict__ xf,
                       u16* __restrict__ xb, int n){
  const int i = (blockIdx.x * 256 + threadIdx.x) << 3;
  if (i >= n) return;
  f32x4 a = *reinterpret_cast<const f32x4*>(x + i);
  f32x4 b = *reinterpret_cast<const f32x4*>(x + i + 4);
  *reinterpret_cast<f32x4*>(xf + i) = a;
  *reinterpret_cast<f32x4*>(xf + i + 4) = b;
  union { u16 us[8]; int4v v; } u;
  #pragma unroll
  for (int j = 0; j < 4; ++j){ u.us[j] = f2bf(a[j]); u.us[4 + j] = f2bf(b[j]); }
  *reinterpret_cast<int4v*>(xb + i) = u.v;
}

// in-place row softmax over bf16 scores[0..q]; zero beyond q; P *= alpha[h]
__global__ __launch_bounds__(128) void k_softmax(u16* __restrict__ sp,
                                                 const float* __restrict__ alphas,
                                                 int pbase){
  const long row = blockIdx.x;
  const int q = (int)(row & (SS - 1));
  const int h = (pbase + (int)(row >> 10)) & (HH - 1);
  u16* rp = sp + row * SS;
  const int t = threadIdx.x;
  const int i0 = t << 3;
  bf16x8 rv = *reinterpret_cast<const bf16x8*>(rp + i0);
  float v[8];
  float lm = -1e30f;
  #pragma unroll
  for (int j = 0; j < 8; ++j){
    union { unsigned u; float f; } c; c.u = ((unsigned)(u16)rv[j]) << 16;
    v[j] = (i0 + j <= q) ? c.f : -1e30f;
    lm = fmaxf(lm, v[j]);
  }
  #pragma unroll
  for (int o = 32; o; o >>= 1) lm = fmaxf(lm, __shfl_xor(lm, o));
  __shared__ float red[2];
  if ((t & 63) == 0) red[t >> 6] = lm;
  __syncthreads();
  const float m = fmaxf(red[0], red[1]);
  float ls = 0.f;
  #pragma unroll
  for (int j = 0; j < 8; ++j){
    float e = exp2f((v[j] - m) * 1.4426950408889634f);
    e = (i0 + j <= q) ? e : 0.f;
    v[j] = e; ls += e;
  }
  #pragma unroll
  for (int o = 32; o; o >>= 1) ls += __shfl_xor(ls, o);
  __syncthreads();
  if ((t & 63) == 0) red[t >> 6] = ls;
  __syncthreads();
  const float inv = alphas[h] / (red[0] + red[1]);
  union { u16 us[8]; bf16x8 v8; } o8;
  #pragma unroll
  for (int j = 0; j < 8; ++j) o8.us[j] = f2bf(v[j] * inv);
  *reinterpret_cast<bf16x8*>(rp + i0) = o8.v8;
}

// per-pair (S,E) -> (E,S), 64x64 bf16 tiles; blockIdx.y = local pair
__global__ __launch_bounds__(256) void k_transpose(const u16* __restrict__ v,
                                                   u16* __restrict__ vt){
  const long bh = blockIdx.y;
  const int ts = blockIdx.x >> 3;
  const int td = blockIdx.x & 7;
  const u16* src = v + bh * (long)(SS * EE) + (long)(ts * 64) * EE + td * 64;
  u16* dst = vt + bh * (long)(SS * EE) + (long)(td * 64) * SS + ts * 64;
  __shared__ __align__(16) u16 tl[64][80];
  const int t = threadIdx.x;
  #pragma unroll
  for (int it = 0; it < 2; ++it){
    int id = t + it * 256;
    int r = id >> 3, c = (id & 7) << 3;
    *reinterpret_cast<int4v*>(&tl[r][c]) =
        *reinterpret_cast<const int4v*>(src + (long)r * EE + c);
  }
  __syncthreads();
  #pragma unroll
  for (int it = 0; it < 2; ++it){
    int id = t + it * 256;
    int r = id >> 3, c = (id & 7) << 3;
    union { u16 us[8]; int4v v; } u;
    #pragma unroll
    for (int j = 0; j < 8; ++j) u.us[j] = tl[c + j][r];
    *reinterpret_cast<int4v*>(dst + (long)r * SS + c) = u.v;
  }
}

__global__ __launch_bounds__(256) void k_ln(const float* __restrict__ src,
                                            const float* __restrict__ g,
                                            const float* __restrict__ b,
                                            float* __restrict__ fdst,
                                            u16* __restrict__ bdst){
  const long row = blockIdx.x;
  const float* x = src + row * EE;
  const int t = threadIdx.x;
  float v0 = x[t], v1 = x[t + 256];
  float s = v0 + v1;
  for (int o = 32; o; o >>= 1) s += __shfl_xor(s, o);
  __shared__ float red[4];
  if ((t & 63) == 0) red[t >> 6] = s;
  __syncthreads();
  const float mean = (red[0] + red[1] + red[2] + red[3]) * (1.0f / EE);
  float d0 = v0 - mean, d1 = v1 - mean;
  float vs = d0 * d0 + d1 * d1;
  for (int o = 32; o; o >>= 1) vs += __shfl_xor(vs, o);
  __syncthreads();
  if ((t & 63) == 0) red[t >> 6] = vs;
  __syncthreads();
  const float var = (red[0] + red[1] + red[2] + red[3]) * (1.0f / EE);
  const float rstd = rsqrtf(var + 1e-5f);
  float o0 = d0 * rstd * g[t] + b[t];
  float o1 = d1 * rstd * g[t + 256] + b[t + 256];
  fdst[row * EE + t] = o0;
  fdst[row * EE + t + 256] = o1;
  bdst[row * EE + t] = f2bf(o0);
  bdst[row * EE + t + 256] = f2bf(o1);
}

__global__ void k_sumbo(const float* __restrict__ bo, float* __restrict__ dst){
  const int o = blockIdx.x * 256 + threadIdx.x;
  if (o >= EE) return;
  float s = 0.f;
  #pragma unroll
  for (int h = 0; h < HH; ++h) s += bo[h * EE + o];
  dst[o] = s;
}

// ---------------------------------------------------------------------------
static inline void gemm_launch(int EP, const GP& p, int batch, hipStream_t st){
  dim3 g((unsigned)((p.M >> 7) * (p.N >> 7)), (unsigned)batch);
  switch (EP){
    case 0: k_gemm<0><<<g, 256, 0, st>>>(p); break;
    case 1: k_gemm<1><<<g, 256, 0, st>>>(p); break;
    case 2: k_gemm<2><<<g, 256, 0, st>>>(p); break;
    case 4: k_gemm<4><<<g, 256, 0, st>>>(p); break;
    case 5: k_gemm<5><<<g, 256, 0, st>>>(p); break;
  }
}

extern "C" void kernel_launch(void* const* d_in, const int* in_sizes, int n_in,
                              void* d_out, int out_size, void* d_ws, size_t ws_size,
                              hipStream_t stream){
  const float* x    = (const float*)d_in[0];
  const float* Wq   = (const float*)d_in[1];
  const float* bq   = (const float*)d_in[2];
  const float* Wk   = (const float*)d_in[3];
  const float* bk   = (const float*)d_in[4];
  const float* Wv   = (const float*)d_in[5];
  const float* bv   = (const float*)d_in[6];
  const float* Wo   = (const float*)d_in[7];
  const float* bo   = (const float*)d_in[8];
  const float* alph = (const float*)d_in[9];
  const float* ln1g = (const float*)d_in[10];
  const float* ln1b = (const float*)d_in[11];
  const float* W1   = (const float*)d_in[12];
  const float* b1   = (const float*)d_in[13];
  const float* W2   = (const float*)d_in[14];
  const float* b2   = (const float*)d_in[15];
  const float* ln2g = (const float*)d_in[16];
  const float* ln2b = (const float*)d_in[17];
  float* out = (float*)d_out;

  const size_t nWh = (size_t)HH * EE * EE;
  const size_t nWf = (size_t)FFD * EE;
  const size_t nX  = (size_t)BB * SS * EE;        // 4,194,304 (also M*N of Wo/FFN2)
  const size_t nQ  = (size_t)BB * HH * SS * EE;
  const size_t nPairV  = (size_t)SS * EE;
  const size_t nPairS  = (size_t)SS * SS;

  const size_t fixedB = 2*nWh*4 + 2*nWf*2
                      + 4*nX + 2*nX
                      + 3 * 2*nQ
                      + 4096 + 32*256;
  const size_t perPairB = 2*nPairS + 2*nPairV;
  int CH = 64;
  while (CH > 1 && fixedB + (size_t)CH * perPairB > ws_size) CH >>= 1;
  const int NC = 64 / CH;

  char* w = (char*)d_ws;
  size_t off = 0;
  auto take = [&](size_t bytes) -> char* {
    char* p = w + off;
    off += (bytes + 255) & ~(size_t)255;
    return p;
  };

  u16* wqb = (u16*)take(2 * nWh);
  u16* wkb = (u16*)take(2 * nWh);
  u16* wvb = (u16*)take(2 * nWh);
  u16* wob = (u16*)take(2 * nWh);
  u16* w1b = (u16*)take(2 * nWf);
  u16* w2b = (u16*)take(2 * nWf);
  float* xf = (float*)take(4 * nX);
  u16* xb   = (u16*)take(2 * nX);
  u16* qb   = (u16*)take(2 * nQ);
  u16* kb   = (u16*)take(2 * nQ);
  u16* vb   = (u16*)take(2 * nQ);
  float* bo_sum = (float*)take(4 * EE);
  u16* vtb  = (u16*)take(2 * nPairV * CH);
  u16* sc   = (u16*)take(2 * nPairS * CH);
  // split-K partials: 4 x (8192x512) f32 = 64 MiB = exactly 2*nQ bytes.
  // Alias kb: K-proj output is fully consumed by the scores GEMMs, which
  // complete before Wo; kb's next use is the WRITE by next layer's K-proj.
  // During FFN2 (reads hid=qb, distinct region) kb is likewise dead.
  float* parts = (float*)kb;
  float* tmp = out;        // d_out doubles as the pre-LN f32 buffer
  u16* hid = qb;           // alias: q dead after scores GEMMs

  auto cvt = [&](const float* s, u16* d, size_t n){
    k_cvt<<<dim3((unsigned)(n / 2048)), 256, 0, stream>>>(s, d, (int)n);
  };
  k_init<<<dim3((unsigned)(nX / 2048)), 256, 0, stream>>>(x, xf, xb, (int)nX);

  for (int i = 0; i < LL; ++i){
    cvt(Wq + i * nWh, wqb, nWh); cvt(Wk + i * nWh, wkb, nWh);
    cvt(Wv + i * nWh, wvb, nWh); cvt(Wo + i * nWh, wob, nWh);
    cvt(W1 + i * nWf, w1b, nWf); cvt(W2 + i * nWf, w2b, nWf);

    // ---- QKV projections: x(8192x512) @ W^T -> (B,H,S,E) bf16 ----
    GP p{};
    p.AsMHi = (long)1024 * EE; p.AsMLo = EE; p.AsH = 0;
    p.BsNHi = (long)EE * EE;   p.BsNLo = EE; p.BsH = 0;
    p.Abatch = p.Bbatch = p.Obatch = 0;
    p.OsMHi = (long)HH * SS * EE; p.OsMLo = EE; p.OsNHi = (long)SS * EE; p.OsNLo = 1;
    p.M = BB * SS; p.N = HH * EE; p.K = EE;
    p.A = xb; p.scale = 1.f; p.causal = 0; p.resid = nullptr; p.Kpart = 0;
    p.B = wqb; p.bias = bq + (size_t)i * HH * EE; p.out = qb;
    gemm_launch(1, p, 1, stream);
    p.B = wkb; p.bias = bk + (size_t)i * HH * EE; p.out = kb;
    gemm_launch(1, p, 1, stream);
    p.B = wvb; p.bias = bv + (size_t)i * HH * EE; p.out = vb;
    gemm_launch(1, p, 1, stream);

    // ---- attention, chunked over (b,h) pairs ----
    for (int c = 0; c < NC; ++c){
      const size_t pbase = (size_t)c * CH;
      const size_t poff = pbase * nPairV;

      k_transpose<<<dim3(128, CH), 256, 0, stream>>>(vb + poff, vtb);

      GP ps{};
      ps.A = qb + poff; ps.B = kb + poff; ps.out = sc;
      ps.AsMHi = 0; ps.AsMLo = EE; ps.AsH = 0;
      ps.BsNHi = (long)512 * EE; ps.BsNLo = EE; ps.BsH = 0;
      ps.Abatch = (long)SS * EE; ps.Bbatch = (long)SS * EE; ps.Obatch = (long)SS * SS;
      ps.OsMHi = 0; ps.OsMLo = SS; ps.OsNHi = 512; ps.OsNLo = 1;
      ps.M = SS; ps.N = SS; ps.K = EE;
      ps.scale = 0.044194173824159216f; ps.causal = 1;
      ps.bias = nullptr; ps.resid = nullptr; ps.Kpart = 0;
      gemm_launch(0, ps, CH, stream);

      k_softmax<<<dim3(CH * SS), 128, 0, stream>>>(sc, alph, (int)pbase);

      GP pv{};
      pv.A = sc; pv.B = vtb; pv.out = vb + poff;
      pv.AsMHi = 0; pv.AsMLo = SS; pv.AsH = 512;
      pv.BsNHi = 0; pv.BsNLo = SS; pv.BsH = 512;
      pv.Abatch = (long)SS * SS; pv.Bbatch = (long)EE * SS; pv.Obatch = (long)SS * EE;
      pv.OsMHi = 0; pv.OsMLo = EE; pv.OsNHi = 0; pv.OsNLo = 1;
      pv.M = SS; pv.N = EE; pv.K = SS; pv.causal = 1;
      pv.scale = 1.f; pv.bias = nullptr; pv.resid = nullptr; pv.Kpart = 0;
      gemm_launch(2, pv, CH, stream);
    }

    k_sumbo<<<dim3(2), 256, 0, stream>>>(bo + (size_t)i * HH * EE, bo_sum);

    // ---- attn_out: split-K x4 (1024 blocks) + reduce(+bo_sum+resid) ----
    GP pw{};
    pw.A = vb; pw.B = wob; pw.out = parts;
    pw.AsMHi = (long)HH * SS * EE; pw.AsMLo = EE; pw.AsH = (long)SS * EE;
    pw.BsNHi = 0; pw.BsNLo = EE; pw.BsH = (long)EE * EE;
    pw.Abatch = pw.Bbatch = 0; pw.Obatch = (long)nX;
    pw.OsMHi = (long)1024 * EE; pw.OsMLo = EE; pw.OsNHi = 0; pw.OsNLo = 1;
    pw.M = BB * SS; pw.N = EE; pw.K = HH * EE; pw.Kpart = (HH * EE) / 4;
    pw.bias = nullptr; pw.resid = nullptr; pw.scale = 1.f; pw.causal = 0;
    gemm_launch(5, pw, 4, stream);
    k_red4<<<dim3((unsigned)(nX / 1024)), 256, 0, stream>>>(parts, bo_sum, xf, tmp, (int)nX);

    k_ln<<<dim3(BB * SS), 256, 0, stream>>>(tmp, ln1g + (size_t)i * EE,
                                            ln1b + (size_t)i * EE, xf, xb);

    // ---- FFN up: relu(x @ W1^T + b1) -> hid bf16 ----
    GP p1{};
    p1.A = xb; p1.B = w1b; p1.out = hid;
    p1.AsMHi = (long)1024 * EE; p1.AsMLo = EE; p1.AsH = 0;
    p1.BsNHi = (long)512 * EE; p1.BsNLo = EE; p1.BsH = 0;
    p1.Abatch = p1.Bbatch = p1.Obatch = 0;
    p1.OsMHi = (long)1024 * FFD; p1.OsMLo = FFD; p1.OsNHi = 512; p1.OsNLo = 1;
    p1.M = BB * SS; p1.N = FFD; p1.K = EE;
    p1.bias = b1 + (size_t)i * FFD; p1.resid = nullptr; p1.scale = 1.f;
    p1.causal = 0; p1.Kpart = 0;
    gemm_launch(4, p1, 1, stream);

    // ---- FFN down: split-K x4 (1024 blocks) + reduce(+b2+resid) ----
    GP p2{};
    p2.A = hid; p2.B = w2b; p2.out = parts;
    p2.AsMHi = (long)1024 * FFD; p2.AsMLo = FFD; p2.AsH = 512;
    p2.BsNHi = 0; p2.BsNLo = FFD; p2.BsH = 512;
    p2.Abatch = p2.Bbatch = 0; p2.Obatch = (long)nX;
    p2.OsMHi = (long)1024 * EE; p2.OsMLo = EE; p2.OsNHi = 0; p2.OsNLo = 1;
    p2.M = BB * SS; p2.N = EE; p2.K = FFD; p2.Kpart = FFD / 4;
    p2.bias = nullptr; p2.resid = nullptr; p2.scale = 1.f; p2.causal = 0;
    gemm_launch(5, p2, 4, stream);
    k_red4<<<dim3((unsigned)(nX / 1024)), 256, 0, stream>>>(parts, b2 + (size_t)i * EE, xf, tmp, (int)nX);

    float* fdst = (i == LL - 1) ? out : xf;
    k_ln<<<dim3(BB * SS), 256, 0, stream>>>(tmp, ln2g + (size_t)i * EE,
                                            ln2b + (size_t)i * EE, fdst, xb);
  }
}

// Round 9
// 2003.523 us; speedup vs baseline: 1.6321x; 1.0276x over previous
//
#include <hip/hip_runtime.h>
#include <hip/hip_bf16.h>
#include <stdint.h>

#define LL 2
#define HH 8
#define EE 512
#define FFD 2048
#define BB 8
#define SS 1024

typedef unsigned short u16;
typedef __attribute__((ext_vector_type(8))) short bf16x8;
typedef __attribute__((ext_vector_type(4))) float f32x4;
typedef __attribute__((ext_vector_type(4))) int int4v;
typedef __attribute__((ext_vector_type(2))) int int2v;

__device__ __forceinline__ u16 f2bf(float f){
  union { float f; unsigned u; } c; c.f = f;
  unsigned r = (c.u + 0x7FFFu + ((c.u >> 16) & 1u)) >> 16;
  return (u16)r;
}

// ---------------------------------------------------------------------------
// 128x128 tile GEMM, C = A(MxK) * B(NxK)^T, bf16 in / f32 accum.
// Round-2-best schedule (measured fastest): single 32KB LDS, __syncthreads
// pair per K-step, global_load_lds width=16, linear LDS dest, pre-swizzled
// global source, swizzled ds_read. No inline asm (m141 lesson).
// EP: 0=bf16 out*scale (+causal tile skip), 1=bf16 out+bias (bias+BiasB*bb),
// 2=bf16 out (+causal K-limit), 4=bf16 out+bias+relu, 5=f32 raw partial
// (split-K: blockIdx.y=part, K range [part*Kpart,+Kpart), out+=part*Obatch)
// ---------------------------------------------------------------------------
struct GP {
  const u16* A; const u16* B;
  const float* bias; const float* resid;
  void* out;
  long AsMHi, AsMLo, AsH;
  long BsNHi, BsNLo, BsH;
  long Abatch, Bbatch, Obatch, BiasB;
  long OsMHi, OsMLo, OsNHi, OsNLo;
  int M, N, K, causal, Kpart;
  float scale;
};

__device__ __forceinline__ int xcd_swz(int bid, int nwg){
  if (nwg < 16) return bid;
  const int q = nwg >> 3, r = nwg & 7;
  const int xcd = bid & 7, loc = bid >> 3;
  return (xcd < r ? xcd * (q + 1) : r * (q + 1) + (xcd - r) * q) + loc;
}

template<int EP>
__global__ __launch_bounds__(256, 3) void k_gemm(GP p){
  const int tilesN = p.N >> 7;
  const int bid = xcd_swz(blockIdx.x, gridDim.x);
  const int m0 = (bid / tilesN) << 7;
  const int n0 = (bid % tilesN) << 7;
  if (EP == 0 && p.causal && n0 > m0) return;   // fully-masked causal tile
  const long bb = blockIdx.y;
  const u16* __restrict__ Ag = p.A + bb * p.Abatch;
  const u16* __restrict__ Bg = p.B + bb * p.Bbatch;

  __shared__ __align__(16) u16 As[128 * 64];
  __shared__ __align__(16) u16 Bs[128 * 64];
  char* AsB = (char*)As;
  char* BsB = (char*)Bs;

  const int t = threadIdx.x;
  const int lane = t & 63;
  const int wv = t >> 6;
  const int wr = (wv >> 1) << 6;   // wave row origin (0/64)
  const int wc = (wv & 1) << 6;    // wave col origin (0/64)

  // staging geometry: wave wv, instr j -> LDS rows (wv*4+j)*8 .. +8
  // lane -> row +(lane>>3), 16B slot (lane&7). Global k pre-XORed so that
  // LDS byte c of row r holds global slab byte c ^ ((r&7)<<4).
  long aoff[4], boff[4];
  #pragma unroll
  for (int j = 0; j < 4; ++j){
    const int r = ((wv << 2) + j) * 8 + (lane >> 3);
    const int kx = ((lane & 7) << 3) ^ ((r & 7) << 3);
    const int gm = m0 + r;
    aoff[j] = (long)(gm >> 10) * p.AsMHi + (long)(gm & 1023) * p.AsMLo + kx;
    const int gn = n0 + r;
    boff[j] = (long)(gn >> 9) * p.BsNHi + (long)(gn & 511) * p.BsNLo + kx;
  }

  int kBeg = 0;
  int Klim = p.K;
  if (EP == 2 && p.causal) { int kl = m0 + 128; Klim = kl < p.K ? kl : p.K; }
  if (EP == 5) { kBeg = (int)bb * p.Kpart; Klim = kBeg + p.Kpart; }

  f32x4 acc[4][4];
  #pragma unroll
  for (int a = 0; a < 4; ++a)
    #pragma unroll
    for (int b = 0; b < 4; ++b)
      acc[a][b] = (f32x4){0.f, 0.f, 0.f, 0.f};

  for (int k0 = kBeg; k0 < Klim; k0 += 64){
    const long ka = (long)(k0 >> 9) * p.AsH + (k0 & 511);
    const long kb = (long)(k0 >> 9) * p.BsH + (k0 & 511);
    __syncthreads();   // LDS free (previous MFMA phase done)
    #pragma unroll
    for (int j = 0; j < 4; ++j){
      const int ldsOff = (((wv << 2) + j) << 9);   // u16 elems, 1KB per instr
      __builtin_amdgcn_global_load_lds(
          (const __attribute__((address_space(1))) void*)(Ag + aoff[j] + ka),
          (__attribute__((address_space(3))) void*)(As + ldsOff), 16, 0, 0);
      __builtin_amdgcn_global_load_lds(
          (const __attribute__((address_space(1))) void*)(Bg + boff[j] + kb),
          (__attribute__((address_space(3))) void*)(Bs + ldsOff), 16, 0, 0);
    }
    __syncthreads();   // tile resident
    #pragma unroll
    for (int kk = 0; kk < 2; ++kk){
      bf16x8 af[4], bv[4];
      #pragma unroll
      for (int mi = 0; mi < 4; ++mi){
        int row = wr + (mi << 4) + (lane & 15);
        int bc = ((kk << 6) + ((lane >> 4) << 4)) ^ ((row & 7) << 4);
        af[mi] = *reinterpret_cast<const bf16x8*>(AsB + row * 128 + bc);
      }
      #pragma unroll
      for (int ni = 0; ni < 4; ++ni){
        int row = wc + (ni << 4) + (lane & 15);
        int bc = ((kk << 6) + ((lane >> 4) << 4)) ^ ((row & 7) << 4);
        bv[ni] = *reinterpret_cast<const bf16x8*>(BsB + row * 128 + bc);
      }
      #pragma unroll
      for (int mi = 0; mi < 4; ++mi)
        #pragma unroll
        for (int ni = 0; ni < 4; ++ni)
          acc[mi][ni] = __builtin_amdgcn_mfma_f32_16x16x32_bf16(af[mi], bv[ni], acc[mi][ni], 0, 0, 0);
    }
  }

  // epilogue: D row=(lane>>4)*4+i, col=lane&15
  const int cm = (lane >> 4) << 2;
  const int cn = lane & 15;
  float biasv[4];
  if (EP == 1 || EP == 4){
    #pragma unroll
    for (int ni = 0; ni < 4; ++ni)
      biasv[ni] = p.bias[bb * p.BiasB + n0 + wc + (ni << 4) + cn];
  }
  #pragma unroll
  for (int mi = 0; mi < 4; ++mi){
    #pragma unroll
    for (int i = 0; i < 4; ++i){
      const int m = m0 + wr + (mi << 4) + cm + i;
      const long ob = bb * p.Obatch + (long)(m >> 10) * p.OsMHi + (long)(m & 1023) * p.OsMLo;
      #pragma unroll
      for (int ni = 0; ni < 4; ++ni){
        const int n = n0 + wc + (ni << 4) + cn;
        const long oa = ob + (long)(n >> 9) * p.OsNHi + (long)(n & 511) * p.OsNLo;
        float v = acc[mi][ni][i];
        if (EP == 0) ((u16*)p.out)[oa] = f2bf(v * p.scale);
        else if (EP == 1) ((u16*)p.out)[oa] = f2bf(v + biasv[ni]);
        else if (EP == 2) ((u16*)p.out)[oa] = f2bf(v);
        else if (EP == 5) ((float*)p.out)[oa] = v;
        else { float r = v + biasv[ni]; ((u16*)p.out)[oa] = f2bf(r > 0.f ? r : 0.f); }
      }
    }
  }
}

// ---------------------------------------------------------------------------
// Fused: sum 4 split-K partials + bias + resid -> LayerNorm -> f32 + bf16 out.
// One block per row (EE=512), 128 threads x f32x4.
__global__ __launch_bounds__(128) void k_redln(const float* __restrict__ part,
                                               const float* __restrict__ bias,
                                               const float* __restrict__ resid,
                                               const float* __restrict__ g,
                                               const float* __restrict__ b,
                                               float* __restrict__ fdst,
                                               u16* __restrict__ bdst){
  const long row = blockIdx.x;
  const int t = threadIdx.x;
  const int col = t << 2;
  const long off = row * EE + col;
  const long nX = (long)BB * SS * EE;
  f32x4 s = *reinterpret_cast<const f32x4*>(part + off);
  #pragma unroll
  for (int q = 1; q < 4; ++q){
    f32x4 v = *reinterpret_cast<const f32x4*>(part + q * nX + off);
    s.x += v.x; s.y += v.y; s.z += v.z; s.w += v.w;
  }
  f32x4 bv = *reinterpret_cast<const f32x4*>(bias + col);
  f32x4 rv = *reinterpret_cast<const f32x4*>(resid + off);
  s.x += bv.x + rv.x; s.y += bv.y + rv.y; s.z += bv.z + rv.z; s.w += bv.w + rv.w;

  float ps = s.x + s.y + s.z + s.w;
  #pragma unroll
  for (int o = 32; o; o >>= 1) ps += __shfl_xor(ps, o);
  __shared__ float red[2], red2[2];
  if ((t & 63) == 0) red[t >> 6] = ps;
  __syncthreads();
  const float mean = (red[0] + red[1]) * (1.0f / EE);
  f32x4 d = { s.x - mean, s.y - mean, s.z - mean, s.w - mean };
  float pv = d.x * d.x + d.y * d.y + d.z * d.z + d.w * d.w;
  #pragma unroll
  for (int o = 32; o; o >>= 1) pv += __shfl_xor(pv, o);
  if ((t & 63) == 0) red2[t >> 6] = pv;
  __syncthreads();
  const float var = (red2[0] + red2[1]) * (1.0f / EE);
  const float rstd = rsqrtf(var + 1e-5f);
  f32x4 gv = *reinterpret_cast<const f32x4*>(g + col);
  f32x4 bb = *reinterpret_cast<const f32x4*>(b + col);
  f32x4 o4 = { d.x * rstd * gv.x + bb.x, d.y * rstd * gv.y + bb.y,
               d.z * rstd * gv.z + bb.z, d.w * rstd * gv.w + bb.w };
  *reinterpret_cast<f32x4*>(fdst + off) = o4;
  union { u16 us[4]; int2v v; } u;
  u.us[0] = f2bf(o4.x); u.us[1] = f2bf(o4.y);
  u.us[2] = f2bf(o4.z); u.us[3] = f2bf(o4.w);
  *reinterpret_cast<int2v*>(bdst + off) = u.v;
}

// ---------------------------------------------------------------------------
// per-layer prep: concat [bq|bk|bv] (3*4096) and bo_sum (512)
__global__ void k_prep(const float* __restrict__ bq, const float* __restrict__ bk,
                       const float* __restrict__ bv, const float* __restrict__ bo,
                       float* __restrict__ catb, float* __restrict__ bos){
  const int j = blockIdx.x * 256 + threadIdx.x;
  if (j < 4096) catb[j] = bq[j];
  else if (j < 8192) catb[j] = bk[j - 4096];
  else if (j < 12288) catb[j] = bv[j - 8192];
  else if (j < 12800){
    const int o = j - 12288;
    float s = 0.f;
    #pragma unroll
    for (int h = 0; h < HH; ++h) s += bo[h * EE + o];
    bos[o] = s;
  }
}

// ---------------------------------------------------------------------------
__global__ void k_cvt(const float* __restrict__ s, u16* __restrict__ d, int n){
  const int i = (blockIdx.x * 256 + threadIdx.x) << 3;
  if (i >= n) return;
  f32x4 a = *reinterpret_cast<const f32x4*>(s + i);
  f32x4 b = *reinterpret_cast<const f32x4*>(s + i + 4);
  union { u16 us[8]; int4v v; } u;
  #pragma unroll
  for (int j = 0; j < 4; ++j){ u.us[j] = f2bf(a[j]); u.us[4 + j] = f2bf(b[j]); }
  *reinterpret_cast<int4v*>(d + i) = u.v;
}

__global__ void k_init(const float* __restrict__ x, float* __restrict__ xf,
                       u16* __restrict__ xb, int n){
  const int i = (blockIdx.x * 256 + threadIdx.x) << 3;
  if (i >= n) return;
  f32x4 a = *reinterpret_cast<const f32x4*>(x + i);
  f32x4 b = *reinterpret_cast<const f32x4*>(x + i + 4);
  *reinterpret_cast<f32x4*>(xf + i) = a;
  *reinterpret_cast<f32x4*>(xf + i + 4) = b;
  union { u16 us[8]; int4v v; } u;
  #pragma unroll
  for (int j = 0; j < 4; ++j){ u.us[j] = f2bf(a[j]); u.us[4 + j] = f2bf(b[j]); }
  *reinterpret_cast<int4v*>(xb + i) = u.v;
}

// in-place row softmax over bf16 scores[0..q]; zero up to the causal
// 128-block limit (PV never reads beyond it); P *= alpha[h]
__global__ __launch_bounds__(128) void k_softmax(u16* __restrict__ sp,
                                                 const float* __restrict__ alphas,
                                                 int pbase){
  const long row = blockIdx.x;
  const int q = (int)(row & (SS - 1));
  const int h = (pbase + (int)(row >> 10)) & (HH - 1);
  const int limit = ((q >> 7) + 1) << 7;   // cols [limit, SS) never read by PV
  u16* rp = sp + row * SS;
  const int t = threadIdx.x;
  const int i0 = t << 3;
  const bool act = i0 < limit;
  float v[8];
  float lm = -1e30f;
  if (act){
    bf16x8 rv = *reinterpret_cast<const bf16x8*>(rp + i0);
    #pragma unroll
    for (int j = 0; j < 8; ++j){
      union { unsigned u; float f; } c; c.u = ((unsigned)(u16)rv[j]) << 16;
      v[j] = (i0 + j <= q) ? c.f : -1e30f;
      lm = fmaxf(lm, v[j]);
    }
  }
  #pragma unroll
  for (int o = 32; o; o >>= 1) lm = fmaxf(lm, __shfl_xor(lm, o));
  __shared__ float red[2];
  if ((t & 63) == 0) red[t >> 6] = lm;
  __syncthreads();
  const float m = fmaxf(red[0], red[1]);
  float ls = 0.f;
  if (act){
    #pragma unroll
    for (int j = 0; j < 8; ++j){
      float e = exp2f((v[j] - m) * 1.4426950408889634f);
      e = (i0 + j <= q) ? e : 0.f;
      v[j] = e; ls += e;
    }
  }
  #pragma unroll
  for (int o = 32; o; o >>= 1) ls += __shfl_xor(ls, o);
  __syncthreads();
  if ((t & 63) == 0) red[t >> 6] = ls;
  __syncthreads();
  const float inv = alphas[h] / (red[0] + red[1]);
  if (act){
    union { u16 us[8]; bf16x8 v8; } o8;
    #pragma unroll
    for (int j = 0; j < 8; ++j) o8.us[j] = f2bf(v[j] * inv);
    *reinterpret_cast<bf16x8*>(rp + i0) = o8.v8;
  }
}

// per-pair (S,E) -> (E,S), 64x64 bf16 tiles; blockIdx.y = local pair
__global__ __launch_bounds__(256) void k_transpose(const u16* __restrict__ v,
                                                   u16* __restrict__ vt){
  const long bh = blockIdx.y;
  const int ts = blockIdx.x >> 3;
  const int td = blockIdx.x & 7;
  const u16* src = v + bh * (long)(SS * EE) + (long)(ts * 64) * EE + td * 64;
  u16* dst = vt + bh * (long)(SS * EE) + (long)(td * 64) * SS + ts * 64;
  __shared__ __align__(16) u16 tl[64][80];
  const int t = threadIdx.x;
  #pragma unroll
  for (int it = 0; it < 2; ++it){
    int id = t + it * 256;
    int r = id >> 3, c = (id & 7) << 3;
    *reinterpret_cast<int4v*>(&tl[r][c]) =
        *reinterpret_cast<const int4v*>(src + (long)r * EE + c);
  }
  __syncthreads();
  #pragma unroll
  for (int it = 0; it < 2; ++it){
    int id = t + it * 256;
    int r = id >> 3, c = (id & 7) << 3;
    union { u16 us[8]; int4v v; } u;
    #pragma unroll
    for (int j = 0; j < 8; ++j) u.us[j] = tl[c + j][r];
    *reinterpret_cast<int4v*>(dst + (long)r * SS + c) = u.v;
  }
}

// ---------------------------------------------------------------------------
static inline void gemm_launch(int EP, const GP& p, int batch, hipStream_t st){
  dim3 g((unsigned)((p.M >> 7) * (p.N >> 7)), (unsigned)batch);
  switch (EP){
    case 0: k_gemm<0><<<g, 256, 0, st>>>(p); break;
    case 1: k_gemm<1><<<g, 256, 0, st>>>(p); break;
    case 2: k_gemm<2><<<g, 256, 0, st>>>(p); break;
    case 4: k_gemm<4><<<g, 256, 0, st>>>(p); break;
    case 5: k_gemm<5><<<g, 256, 0, st>>>(p); break;
  }
}

extern "C" void kernel_launch(void* const* d_in, const int* in_sizes, int n_in,
                              void* d_out, int out_size, void* d_ws, size_t ws_size,
                              hipStream_t stream){
  const float* x    = (const float*)d_in[0];
  const float* Wq   = (const float*)d_in[1];
  const float* bq   = (const float*)d_in[2];
  const float* Wk   = (const float*)d_in[3];
  const float* bk   = (const float*)d_in[4];
  const float* Wv   = (const float*)d_in[5];
  const float* bv   = (const float*)d_in[6];
  const float* Wo   = (const float*)d_in[7];
  const float* bo   = (const float*)d_in[8];
  const float* alph = (const float*)d_in[9];
  const float* ln1g = (const float*)d_in[10];
  const float* ln1b = (const float*)d_in[11];
  const float* W1   = (const float*)d_in[12];
  const float* b1   = (const float*)d_in[13];
  const float* W2   = (const float*)d_in[14];
  const float* b2   = (const float*)d_in[15];
  const float* ln2g = (const float*)d_in[16];
  const float* ln2b = (const float*)d_in[17];
  float* out = (float*)d_out;

  const size_t nWh = (size_t)HH * EE * EE;
  const size_t nWf = (size_t)FFD * EE;
  const size_t nX  = (size_t)BB * SS * EE;
  const size_t nQ  = (size_t)BB * HH * SS * EE;
  const size_t nPairV  = (size_t)SS * EE;
  const size_t nPairS  = (size_t)SS * SS;

  const size_t fixedB = 2*nWh*4 + 2*nWf*2
                      + 4*nX + 2*nX
                      + 3 * 2*nQ
                      + 4096 + 4*3*HH*EE + 64*256;
  const size_t perPairB = 2*nPairS + 2*nPairV;
  int CH = 64;
  while (CH > 1 && fixedB + (size_t)CH * perPairB > ws_size) CH >>= 1;
  const int NC = 64 / CH;

  char* w = (char*)d_ws;
  size_t off = 0;
  auto take = [&](size_t bytes) -> char* {
    char* p = w + off;
    off += (bytes + 255) & ~(size_t)255;
    return p;
  };

  u16* wqb = (u16*)take(2 * nWh);   // wq|wk|wv contiguous (4MiB each)
  u16* wkb = (u16*)take(2 * nWh);
  u16* wvb = (u16*)take(2 * nWh);
  u16* wob = (u16*)take(2 * nWh);
  u16* w1b = (u16*)take(2 * nWf);
  u16* w2b = (u16*)take(2 * nWf);
  float* xf = (float*)take(4 * nX);
  u16* xb   = (u16*)take(2 * nX);
  u16* qb   = (u16*)take(2 * nQ);   // q|k|v contiguous (64MiB each)
  u16* kb   = (u16*)take(2 * nQ);
  u16* vb   = (u16*)take(2 * nQ);
  float* bo_sum = (float*)take(4 * EE);
  float* qkvbias = (float*)take(4 * 3 * HH * EE);
  u16* vtb  = (u16*)take(2 * nPairV * CH);
  u16* sc   = (u16*)take(2 * nPairS * CH);
  // split-K partials: 4 x (8192x512) f32 = 64 MiB = exactly 2*nQ bytes.
  // Alias kb: scores GEMMs (kb's only readers) finish before Wo; during
  // FFN2 kb is also dead. Next use is the WRITE by next layer's K-proj.
  float* parts = (float*)kb;
  u16* hid = qb;   // alias: q dead after scores GEMMs

  auto cvt = [&](const float* s, u16* d, size_t n){
    k_cvt<<<dim3((unsigned)(n / 2048)), 256, 0, stream>>>(s, d, (int)n);
  };
  k_init<<<dim3((unsigned)(nX / 2048)), 256, 0, stream>>>(x, xf, xb, (int)nX);

  for (int i = 0; i < LL; ++i){
    cvt(Wq + i * nWh, wqb, nWh); cvt(Wk + i * nWh, wkb, nWh);
    cvt(Wv + i * nWh, wvb, nWh); cvt(Wo + i * nWh, wob, nWh);
    cvt(W1 + i * nWf, w1b, nWf); cvt(W2 + i * nWf, w2b, nWf);
    k_prep<<<dim3(50), 256, 0, stream>>>(bq + (size_t)i * HH * EE,
                                         bk + (size_t)i * HH * EE,
                                         bv + (size_t)i * HH * EE,
                                         bo + (size_t)i * HH * EE,
                                         qkvbias, bo_sum);

    // ---- QKV: one batched GEMM (blockIdx.y = q/k/v) ----
    GP p{};
    p.AsMHi = (long)1024 * EE; p.AsMLo = EE; p.AsH = 0;
    p.BsNHi = (long)EE * EE;   p.BsNLo = EE; p.BsH = 0;
    p.Abatch = 0; p.Bbatch = (long)nWh; p.Obatch = (long)nQ;
    p.BiasB = (long)HH * EE;
    p.OsMHi = (long)HH * SS * EE; p.OsMLo = EE; p.OsNHi = (long)SS * EE; p.OsNLo = 1;
    p.M = BB * SS; p.N = HH * EE; p.K = EE;
    p.A = xb; p.B = wqb; p.bias = qkvbias; p.out = qb;
    p.scale = 1.f; p.causal = 0; p.resid = nullptr; p.Kpart = 0;
    gemm_launch(1, p, 3, stream);

    // ---- attention, chunked over (b,h) pairs ----
    for (int c = 0; c < NC; ++c){
      const size_t pbase = (size_t)c * CH;
      const size_t poff = pbase * nPairV;

      k_transpose<<<dim3(128, CH), 256, 0, stream>>>(vb + poff, vtb);

      GP ps{};
      ps.A = qb + poff; ps.B = kb + poff; ps.out = sc;
      ps.AsMHi = 0; ps.AsMLo = EE; ps.AsH = 0;
      ps.BsNHi = (long)512 * EE; ps.BsNLo = EE; ps.BsH = 0;
      ps.Abatch = (long)SS * EE; ps.Bbatch = (long)SS * EE; ps.Obatch = (long)SS * SS;
      ps.BiasB = 0;
      ps.OsMHi = 0; ps.OsMLo = SS; ps.OsNHi = 512; ps.OsNLo = 1;
      ps.M = SS; ps.N = SS; ps.K = EE;
      ps.scale = 0.044194173824159216f; ps.causal = 1;
      ps.bias = nullptr; ps.resid = nullptr; ps.Kpart = 0;
      gemm_launch(0, ps, CH, stream);

      k_softmax<<<dim3(CH * SS), 128, 0, stream>>>(sc, alph, (int)pbase);

      GP pv{};
      pv.A = sc; pv.B = vtb; pv.out = vb + poff;
      pv.AsMHi = 0; pv.AsMLo = SS; pv.AsH = 512;
      pv.BsNHi = 0; pv.BsNLo = SS; pv.BsH = 512;
      pv.Abatch = (long)SS * SS; pv.Bbatch = (long)EE * SS; pv.Obatch = (long)SS * EE;
      pv.BiasB = 0;
      pv.OsMHi = 0; pv.OsMLo = EE; pv.OsNHi = 0; pv.OsNLo = 1;
      pv.M = SS; pv.N = EE; pv.K = SS; pv.causal = 1;
      pv.scale = 1.f; pv.bias = nullptr; pv.resid = nullptr; pv.Kpart = 0;
      gemm_launch(2, pv, CH, stream);
    }

    // ---- attn_out: split-K x4 + fused reduce+bias+resid+LN1 ----
    GP pw{};
    pw.A = vb; pw.B = wob; pw.out = parts;
    pw.AsMHi = (long)HH * SS * EE; pw.AsMLo = EE; pw.AsH = (long)SS * EE;
    pw.BsNHi = 0; pw.BsNLo = EE; pw.BsH = (long)EE * EE;
    pw.Abatch = pw.Bbatch = 0; pw.Obatch = (long)nX; pw.BiasB = 0;
    pw.OsMHi = (long)1024 * EE; pw.OsMLo = EE; pw.OsNHi = 0; pw.OsNLo = 1;
    pw.M = BB * SS; pw.N = EE; pw.K = HH * EE; pw.Kpart = (HH * EE) / 4;
    pw.bias = nullptr; pw.resid = nullptr; pw.scale = 1.f; pw.causal = 0;
    gemm_launch(5, pw, 4, stream);
    k_redln<<<dim3(BB * SS), 128, 0, stream>>>(parts, bo_sum, xf,
                                               ln1g + (size_t)i * EE,
                                               ln1b + (size_t)i * EE, xf, xb);

    // ---- FFN up: relu(x @ W1^T + b1) -> hid bf16 ----
    GP p1{};
    p1.A = xb; p1.B = w1b; p1.out = hid;
    p1.AsMHi = (long)1024 * EE; p1.AsMLo = EE; p1.AsH = 0;
    p1.BsNHi = (long)512 * EE; p1.BsNLo = EE; p1.BsH = 0;
    p1.Abatch = p1.Bbatch = p1.Obatch = 0; p1.BiasB = 0;
    p1.OsMHi = (long)1024 * FFD; p1.OsMLo = FFD; p1.OsNHi = 512; p1.OsNLo = 1;
    p1.M = BB * SS; p1.N = FFD; p1.K = EE;
    p1.bias = b1 + (size_t)i * FFD; p1.resid = nullptr; p1.scale = 1.f;
    p1.causal = 0; p1.Kpart = 0;
    gemm_launch(4, p1, 1, stream);

    // ---- FFN down: split-K x4 + fused reduce+bias+resid+LN2 ----
    GP p2{};
    p2.A = hid; p2.B = w2b; p2.out = parts;
    p2.AsMHi = (long)1024 * FFD; p2.AsMLo = FFD; p2.AsH = 512;
    p2.BsNHi = 0; p2.BsNLo = FFD; p2.BsH = 512;
    p2.Abatch = p2.Bbatch = 0; p2.Obatch = (long)nX; p2.BiasB = 0;
    p2.OsMHi = (long)1024 * EE; p2.OsMLo = EE; p2.OsNHi = 0; p2.OsNLo = 1;
    p2.M = BB * SS; p2.N = EE; p2.K = FFD; p2.Kpart = FFD / 4;
    p2.bias = nullptr; p2.resid = nullptr; p2.scale = 1.f; p2.causal = 0;
    gemm_launch(5, p2, 4, stream);
    float* fdst = (i == LL - 1) ? out : xf;
    k_redln<<<dim3(BB * SS), 128, 0, stream>>>(parts, b2 + (size_t)i * EE, xf,
                                               ln2g + (size_t)i * EE,
                                               ln2b + (size_t)i * EE, fdst, xb);
  }
}

// Round 11
// 1254.724 us; speedup vs baseline: 2.6061x; 1.5968x over previous
//
#include <hip/hip_runtime.h>
#include <hip/hip_bf16.h>
#include <stdint.h>

#define LL 2
#define HH 8
#define EE 512
#define FFD 2048
#define BB 8
#define SS 1024
#define CB 2            // batches per attention chunk
#define NCH (BB / CB)   // 4 chunks
#define PAIRS (CB * HH) // 16 (b,h) pairs per chunk

typedef unsigned short u16;
typedef __attribute__((ext_vector_type(8))) short bf16x8;
typedef __attribute__((ext_vector_type(4))) float f32x4;
typedef __attribute__((ext_vector_type(4))) int int4v;
typedef __attribute__((ext_vector_type(2))) int int2v;

__device__ __forceinline__ u16 f2bf(float f){
  union { float f; unsigned u; } c; c.f = f;
  unsigned r = (c.u + 0x7FFFu + ((c.u >> 16) & 1u)) >> 16;
  return (u16)r;
}

// ---------------------------------------------------------------------------
// 128x128 tile GEMM, C = A(MxK) * B(NxK)^T, bf16 in / f32 accum.
// Round-2-best schedule (measured fastest): single 32KB LDS, __syncthreads
// pair per K-step, global_load_lds width=16, linear LDS dest, pre-swizzled
// global source, swizzled ds_read. No inline asm (m141 lesson).
// EP: 0=bf16 out*scale (+causal tile skip), 1=bf16 out+bias (bias+BiasB*bb),
// 2=bf16 out (+causal K-limit), 4=bf16 out+bias+relu, 5=f32 raw partial
// (split-K: blockIdx.y=part, K range [part*Kpart,+Kpart), out+=part*Obatch)
// ---------------------------------------------------------------------------
struct GP {
  const u16* A; const u16* B;
  const float* bias; const float* resid;
  void* out;
  long AsMHi, AsMLo, AsH;
  long BsNHi, BsNLo, BsH;
  long Abatch, Bbatch, Obatch, BiasB;
  long OsMHi, OsMLo, OsNHi, OsNLo;
  int M, N, K, causal, Kpart;
  float scale;
};

__device__ __forceinline__ int xcd_swz(int bid, int nwg){
  if (nwg < 16) return bid;
  const int q = nwg >> 3, r = nwg & 7;
  const int xcd = bid & 7, loc = bid >> 3;
  return (xcd < r ? xcd * (q + 1) : r * (q + 1) + (xcd - r) * q) + loc;
}

template<int EP>
__global__ __launch_bounds__(256, 3) void k_gemm(GP p){
  const int tilesN = p.N >> 7;
  const int bid = xcd_swz(blockIdx.x, gridDim.x);
  const int m0 = (bid / tilesN) << 7;
  const int n0 = (bid % tilesN) << 7;
  if (EP == 0 && p.causal && n0 > m0) return;   // fully-masked causal tile
  const long bb = blockIdx.y;
  const u16* __restrict__ Ag = p.A + bb * p.Abatch;
  const u16* __restrict__ Bg = p.B + bb * p.Bbatch;

  __shared__ __align__(16) u16 As[128 * 64];
  __shared__ __align__(16) u16 Bs[128 * 64];
  char* AsB = (char*)As;
  char* BsB = (char*)Bs;

  const int t = threadIdx.x;
  const int lane = t & 63;
  const int wv = t >> 6;
  const int wr = (wv >> 1) << 6;   // wave row origin (0/64)
  const int wc = (wv & 1) << 6;    // wave col origin (0/64)

  // staging geometry: wave wv, instr j -> LDS rows (wv*4+j)*8 .. +8
  // lane -> row +(lane>>3), 16B slot (lane&7). Global k pre-XORed so that
  // LDS byte c of row r holds global slab byte c ^ ((r&7)<<4).
  long aoff[4], boff[4];
  #pragma unroll
  for (int j = 0; j < 4; ++j){
    const int r = ((wv << 2) + j) * 8 + (lane >> 3);
    const int kx = ((lane & 7) << 3) ^ ((r & 7) << 3);
    const int gm = m0 + r;
    aoff[j] = (long)(gm >> 10) * p.AsMHi + (long)(gm & 1023) * p.AsMLo + kx;
    const int gn = n0 + r;
    boff[j] = (long)(gn >> 9) * p.BsNHi + (long)(gn & 511) * p.BsNLo + kx;
  }

  int kBeg = 0;
  int Klim = p.K;
  if (EP == 2 && p.causal) { int kl = m0 + 128; Klim = kl < p.K ? kl : p.K; }
  if (EP == 5) { kBeg = (int)bb * p.Kpart; Klim = kBeg + p.Kpart; }

  f32x4 acc[4][4];
  #pragma unroll
  for (int a = 0; a < 4; ++a)
    #pragma unroll
    for (int b = 0; b < 4; ++b)
      acc[a][b] = (f32x4){0.f, 0.f, 0.f, 0.f};

  for (int k0 = kBeg; k0 < Klim; k0 += 64){
    const long ka = (long)(k0 >> 9) * p.AsH + (k0 & 511);
    const long kb = (long)(k0 >> 9) * p.BsH + (k0 & 511);
    __syncthreads();   // LDS free (previous MFMA phase done)
    #pragma unroll
    for (int j = 0; j < 4; ++j){
      const int ldsOff = (((wv << 2) + j) << 9);   // u16 elems, 1KB per instr
      __builtin_amdgcn_global_load_lds(
          (const __attribute__((address_space(1))) void*)(Ag + aoff[j] + ka),
          (__attribute__((address_space(3))) void*)(As + ldsOff), 16, 0, 0);
      __builtin_amdgcn_global_load_lds(
          (const __attribute__((address_space(1))) void*)(Bg + boff[j] + kb),
          (__attribute__((address_space(3))) void*)(Bs + ldsOff), 16, 0, 0);
    }
    __syncthreads();   // tile resident
    #pragma unroll
    for (int kk = 0; kk < 2; ++kk){
      bf16x8 af[4], bv[4];
      #pragma unroll
      for (int mi = 0; mi < 4; ++mi){
        int row = wr + (mi << 4) + (lane & 15);
        int bc = ((kk << 6) + ((lane >> 4) << 4)) ^ ((row & 7) << 4);
        af[mi] = *reinterpret_cast<const bf16x8*>(AsB + row * 128 + bc);
      }
      #pragma unroll
      for (int ni = 0; ni < 4; ++ni){
        int row = wc + (ni << 4) + (lane & 15);
        int bc = ((kk << 6) + ((lane >> 4) << 4)) ^ ((row & 7) << 4);
        bv[ni] = *reinterpret_cast<const bf16x8*>(BsB + row * 128 + bc);
      }
      #pragma unroll
      for (int mi = 0; mi < 4; ++mi)
        #pragma unroll
        for (int ni = 0; ni < 4; ++ni)
          acc[mi][ni] = __builtin_amdgcn_mfma_f32_16x16x32_bf16(af[mi], bv[ni], acc[mi][ni], 0, 0, 0);
    }
  }

  // epilogue: D row=(lane>>4)*4+i, col=lane&15
  const int cm = (lane >> 4) << 2;
  const int cn = lane & 15;
  float biasv[4];
  if (EP == 1 || EP == 4){
    #pragma unroll
    for (int ni = 0; ni < 4; ++ni)
      biasv[ni] = p.bias[bb * p.BiasB + n0 + wc + (ni << 4) + cn];
  }
  #pragma unroll
  for (int mi = 0; mi < 4; ++mi){
    #pragma unroll
    for (int i = 0; i < 4; ++i){
      const int m = m0 + wr + (mi << 4) + cm + i;
      const long ob = bb * p.Obatch + (long)(m >> 10) * p.OsMHi + (long)(m & 1023) * p.OsMLo;
      #pragma unroll
      for (int ni = 0; ni < 4; ++ni){
        const int n = n0 + wc + (ni << 4) + cn;
        const long oa = ob + (long)(n >> 9) * p.OsNHi + (long)(n & 511) * p.OsNLo;
        float v = acc[mi][ni][i];
        if (EP == 0) ((u16*)p.out)[oa] = f2bf(v * p.scale);
        else if (EP == 1) ((u16*)p.out)[oa] = f2bf(v + biasv[ni]);
        else if (EP == 2) ((u16*)p.out)[oa] = f2bf(v);
        else if (EP == 5) ((float*)p.out)[oa] = v;
        else { float r = v + biasv[ni]; ((u16*)p.out)[oa] = f2bf(r > 0.f ? r : 0.f); }
      }
    }
  }
}

// ---------------------------------------------------------------------------
// Fused: sum 4 split-K partials + bias + resid -> LayerNorm -> f32 + bf16 out.
__global__ __launch_bounds__(128) void k_redln(const float* __restrict__ part,
                                               const float* __restrict__ bias,
                                               const float* __restrict__ resid,
                                               const float* __restrict__ g,
                                               const float* __restrict__ b,
                                               float* __restrict__ fdst,
                                               u16* __restrict__ bdst){
  const long row = blockIdx.x;
  const int t = threadIdx.x;
  const int col = t << 2;
  const long off = row * EE + col;
  const long nX = (long)BB * SS * EE;
  f32x4 s = *reinterpret_cast<const f32x4*>(part + off);
  #pragma unroll
  for (int q = 1; q < 4; ++q){
    f32x4 v = *reinterpret_cast<const f32x4*>(part + q * nX + off);
    s.x += v.x; s.y += v.y; s.z += v.z; s.w += v.w;
  }
  f32x4 bv = *reinterpret_cast<const f32x4*>(bias + col);
  f32x4 rv = *reinterpret_cast<const f32x4*>(resid + off);
  s.x += bv.x + rv.x; s.y += bv.y + rv.y; s.z += bv.z + rv.z; s.w += bv.w + rv.w;

  float ps = s.x + s.y + s.z + s.w;
  #pragma unroll
  for (int o = 32; o; o >>= 1) ps += __shfl_xor(ps, o);
  __shared__ float red[2], red2[2];
  if ((t & 63) == 0) red[t >> 6] = ps;
  __syncthreads();
  const float mean = (red[0] + red[1]) * (1.0f / EE);
  f32x4 d = { s.x - mean, s.y - mean, s.z - mean, s.w - mean };
  float pv = d.x * d.x + d.y * d.y + d.z * d.z + d.w * d.w;
  #pragma unroll
  for (int o = 32; o; o >>= 1) pv += __shfl_xor(pv, o);
  if ((t & 63) == 0) red2[t >> 6] = pv;
  __syncthreads();
  const float var = (red2[0] + red2[1]) * (1.0f / EE);
  const float rstd = rsqrtf(var + 1e-5f);
  f32x4 gv = *reinterpret_cast<const f32x4*>(g + col);
  f32x4 bb = *reinterpret_cast<const f32x4*>(b + col);
  f32x4 o4 = { d.x * rstd * gv.x + bb.x, d.y * rstd * gv.y + bb.y,
               d.z * rstd * gv.z + bb.z, d.w * rstd * gv.w + bb.w };
  *reinterpret_cast<f32x4*>(fdst + off) = o4;
  union { u16 us[4]; int2v v; } u;
  u.us[0] = f2bf(o4.x); u.us[1] = f2bf(o4.y);
  u.us[2] = f2bf(o4.z); u.us[3] = f2bf(o4.w);
  *reinterpret_cast<int2v*>(bdst + off) = u.v;
}

// ---------------------------------------------------------------------------
// one-shot prep for BOTH layers: concat [bq|bk|bv] per layer and bo_sum
__global__ void k_prep(const float* __restrict__ bq, const float* __restrict__ bk,
                       const float* __restrict__ bv, const float* __restrict__ bo,
                       float* __restrict__ catb, float* __restrict__ bos){
  const int j = blockIdx.x * 256 + threadIdx.x;
  if (j >= 2 * 12800) return;
  const int L = j / 12800;
  const int r = j - L * 12800;
  const int lw = L * HH * EE;      // 4096 per layer
  float* catL = catb + (size_t)L * 3 * HH * EE;
  if (r < 4096) catL[r] = bq[lw + r];
  else if (r < 8192) catL[r] = bk[lw + r - 4096];
  else if (r < 12288) catL[r] = bv[lw + r - 8192];
  else {
    const int o = r - 12288;
    float s = 0.f;
    #pragma unroll
    for (int h = 0; h < HH; ++h) s += bo[lw + h * EE + o];
    bos[L * EE + o] = s;
  }
}

// ---------------------------------------------------------------------------
__global__ void k_cvt(const float* __restrict__ s, u16* __restrict__ d, int n){
  const int i = (blockIdx.x * 256 + threadIdx.x) << 3;
  if (i >= n) return;
  f32x4 a = *reinterpret_cast<const f32x4*>(s + i);
  f32x4 b = *reinterpret_cast<const f32x4*>(s + i + 4);
  union { u16 us[8]; int4v v; } u;
  #pragma unroll
  for (int j = 0; j < 4; ++j){ u.us[j] = f2bf(a[j]); u.us[4 + j] = f2bf(b[j]); }
  *reinterpret_cast<int4v*>(d + i) = u.v;
}

__global__ void k_init(const float* __restrict__ x, float* __restrict__ xf,
                       u16* __restrict__ xb, int n){
  const int i = (blockIdx.x * 256 + threadIdx.x) << 3;
  if (i >= n) return;
  f32x4 a = *reinterpret_cast<const f32x4*>(x + i);
  f32x4 b = *reinterpret_cast<const f32x4*>(x + i + 4);
  *reinterpret_cast<f32x4*>(xf + i) = a;
  *reinterpret_cast<f32x4*>(xf + i + 4) = b;
  union { u16 us[8]; int4v v; } u;
  #pragma unroll
  for (int j = 0; j < 4; ++j){ u.us[j] = f2bf(a[j]); u.us[4 + j] = f2bf(b[j]); }
  *reinterpret_cast<int4v*>(xb + i) = u.v;
}

// in-place row softmax over bf16 scores[0..q], 2 rows per block (256 thr);
// pair = row>>10 within chunk, ordered (b_local, h) -> h = pair & 7
__global__ __launch_bounds__(256) void k_softmax(u16* __restrict__ sp,
                                                 const float* __restrict__ alphas){
  const int sub = threadIdx.x >> 7;            // row within block (0/1)
  const long row = (long)blockIdx.x * 2 + sub;
  const int t = threadIdx.x & 127;
  const int q = (int)(row & (SS - 1));
  const int h = (int)(row >> 10) & (HH - 1);
  const int limit = ((q >> 7) + 1) << 7;       // cols [limit, SS) never read
  u16* rp = sp + row * SS;
  const int i0 = t << 3;
  const bool act = i0 < limit;
  float v[8];
  float lm = -1e30f;
  if (act){
    bf16x8 rv = *reinterpret_cast<const bf16x8*>(rp + i0);
    #pragma unroll
    for (int j = 0; j < 8; ++j){
      union { unsigned u; float f; } c; c.u = ((unsigned)(u16)rv[j]) << 16;
      v[j] = (i0 + j <= q) ? c.f : -1e30f;
      lm = fmaxf(lm, v[j]);
    }
  }
  #pragma unroll
  for (int o = 32; o; o >>= 1) lm = fmaxf(lm, __shfl_xor(lm, o));
  __shared__ float red[4];
  if ((threadIdx.x & 63) == 0) red[threadIdx.x >> 6] = lm;
  __syncthreads();
  const float m = fmaxf(red[sub * 2], red[sub * 2 + 1]);
  float ls = 0.f;
  if (act){
    #pragma unroll
    for (int j = 0; j < 8; ++j){
      float e = exp2f((v[j] - m) * 1.4426950408889634f);
      e = (i0 + j <= q) ? e : 0.f;
      v[j] = e; ls += e;
    }
  }
  #pragma unroll
  for (int o = 32; o; o >>= 1) ls += __shfl_xor(ls, o);
  __syncthreads();
  if ((threadIdx.x & 63) == 0) red[threadIdx.x >> 6] = ls;
  __syncthreads();
  const float inv = alphas[h] / (red[sub * 2] + red[sub * 2 + 1]);
  if (act){
    union { u16 us[8]; bf16x8 v8; } o8;
    #pragma unroll
    for (int j = 0; j < 8; ++j) o8.us[j] = f2bf(v[j] * inv);
    *reinterpret_cast<bf16x8*>(rp + i0) = o8.v8;
  }
}

// per-pair (S,E) -> (E,S), 64x64 bf16 tiles; blockIdx.y = local pair
__global__ __launch_bounds__(256) void k_transpose(const u16* __restrict__ v,
                                                   u16* __restrict__ vt){
  const long bh = blockIdx.y;
  const int ts = blockIdx.x >> 3;
  const int td = blockIdx.x & 7;
  const u16* src = v + bh * (long)(SS * EE) + (long)(ts * 64) * EE + td * 64;
  u16* dst = vt + bh * (long)(SS * EE) + (long)(td * 64) * SS + ts * 64;
  __shared__ __align__(16) u16 tl[64][80];
  const int t = threadIdx.x;
  #pragma unroll
  for (int it = 0; it < 2; ++it){
    int id = t + it * 256;
    int r = id >> 3, c = (id & 7) << 3;
    *reinterpret_cast<int4v*>(&tl[r][c]) =
        *reinterpret_cast<const int4v*>(src + (long)r * EE + c);
  }
  __syncthreads();
  #pragma unroll
  for (int it = 0; it < 2; ++it){
    int id = t + it * 256;
    int r = id >> 3, c = (id & 7) << 3;
    union { u16 us[8]; int4v v; } u;
    #pragma unroll
    for (int j = 0; j < 8; ++j) u.us[j] = tl[c + j][r];
    *reinterpret_cast<int4v*>(dst + (long)r * SS + c) = u.v;
  }
}

// ---------------------------------------------------------------------------
static inline void gemm_launch(int EP, const GP& p, int batch, hipStream_t st){
  dim3 g((unsigned)((p.M >> 7) * (p.N >> 7)), (unsigned)batch);
  switch (EP){
    case 0: k_gemm<0><<<g, 256, 0, st>>>(p); break;
    case 1: k_gemm<1><<<g, 256, 0, st>>>(p); break;
    case 2: k_gemm<2><<<g, 256, 0, st>>>(p); break;
    case 4: k_gemm<4><<<g, 256, 0, st>>>(p); break;
    case 5: k_gemm<5><<<g, 256, 0, st>>>(p); break;
  }
}

extern "C" void kernel_launch(void* const* d_in, const int* in_sizes, int n_in,
                              void* d_out, int out_size, void* d_ws, size_t ws_size,
                              hipStream_t stream){
  const float* x    = (const float*)d_in[0];
  const float* Wq   = (const float*)d_in[1];
  const float* bq   = (const float*)d_in[2];
  const float* Wk   = (const float*)d_in[3];
  const float* bk   = (const float*)d_in[4];
  const float* Wv   = (const float*)d_in[5];
  const float* bv   = (const float*)d_in[6];
  const float* Wo   = (const float*)d_in[7];
  const float* bo   = (const float*)d_in[8];
  const float* alph = (const float*)d_in[9];
  const float* ln1g = (const float*)d_in[10];
  const float* ln1b = (const float*)d_in[11];
  const float* W1   = (const float*)d_in[12];
  const float* b1   = (const float*)d_in[13];
  const float* W2   = (const float*)d_in[14];
  const float* b2   = (const float*)d_in[15];
  const float* ln2g = (const float*)d_in[16];
  const float* ln2b = (const float*)d_in[17];
  float* out = (float*)d_out;

  const size_t nWh = (size_t)HH * EE * EE;           // 2,097,152
  const size_t nWf = (size_t)FFD * EE;               // 1,048,576
  const size_t nX  = (size_t)BB * SS * EE;           // 4,194,304
  const size_t nQ  = (size_t)BB * HH * SS * EE;      // 33,554,432
  const size_t nChQ = (size_t)CB * HH * SS * EE;     // 8,388,608 per chunk buf
  const size_t nScC = (size_t)PAIRS * SS * SS;       // 16,777,216 scores/chunk

  // Static footprint ~235 MB (known-good ws floor ~250 MB from rounds 2-8):
  //   weights (both layers) 42MB + xf 16.8 + xb 8.4 + ao 67.1
  //   + qc/kc/vc/vtc 67.1 + sc 33.6 + misc
  char* w = (char*)d_ws;
  size_t off = 0;
  auto take = [&](size_t bytes) -> char* {
    char* p = w + off;
    off += (bytes + 255) & ~(size_t)255;
    return p;
  };

  // weight buffers hold BOTH layers [L0|L1]; wqb/wkb/wvb adjacent & pad-free
  // (each 4*nWh bytes, 256B-divisible) -> batched-QKV B stride = 2*nWh elems
  u16* wqb = (u16*)take(4 * nWh);
  u16* wkb = (u16*)take(4 * nWh);
  u16* wvb = (u16*)take(4 * nWh);
  u16* wob = (u16*)take(4 * nWh);
  u16* w1b = (u16*)take(4 * nWf);
  u16* w2b = (u16*)take(4 * nWf);
  float* xf = (float*)take(4 * nX);
  u16* xb   = (u16*)take(2 * nX);
  u16* ao   = (u16*)take(2 * nQ);     // PV output, (B,H,S,E) bf16
  u16* qc   = (u16*)take(2 * nChQ);   // per-chunk Q/K/V/Vt — contiguous
  u16* kc   = (u16*)take(2 * nChQ);   //   (16,777,216 B each, 256-divisible)
  u16* vc   = (u16*)take(2 * nChQ);
  u16* vtc  = (u16*)take(2 * nChQ);
  u16* sc   = (u16*)take(2 * nScC);   // per-chunk bf16 scores (in-place P)
  float* bo_sum  = (float*)take(4 * 2 * EE);
  float* qkvbias = (float*)take(4 * 2 * 3 * HH * EE);
  // split-K partials: 4 x nX f32 = 67,108,864 B = exactly the qc..vtc span
  // (dead during Wo and FFN2 — attention fully consumed them into ao).
  float* parts = (float*)qc;
  // FFN hidden: 8192x2048 bf16 = 33,554,432 B = exactly sc (dead after PV).
  u16* hid = sc;

  // ---- one-shot: input cast + all weight conversion + bias prep ----
  k_init<<<dim3((unsigned)(nX / 2048)), 256, 0, stream>>>(x, xf, xb, (int)nX);
  k_cvt<<<dim3((unsigned)(2 * nWh / 2048)), 256, 0, stream>>>(Wq, wqb, (int)(2 * nWh));
  k_cvt<<<dim3((unsigned)(2 * nWh / 2048)), 256, 0, stream>>>(Wk, wkb, (int)(2 * nWh));
  k_cvt<<<dim3((unsigned)(2 * nWh / 2048)), 256, 0, stream>>>(Wv, wvb, (int)(2 * nWh));
  k_cvt<<<dim3((unsigned)(2 * nWh / 2048)), 256, 0, stream>>>(Wo, wob, (int)(2 * nWh));
  k_cvt<<<dim3((unsigned)(2 * nWf / 2048)), 256, 0, stream>>>(W1, w1b, (int)(2 * nWf));
  k_cvt<<<dim3((unsigned)(2 * nWf / 2048)), 256, 0, stream>>>(W2, w2b, (int)(2 * nWf));
  k_prep<<<dim3(100), 256, 0, stream>>>(bq, bk, bv, bo, qkvbias, bo_sum);

  for (int i = 0; i < LL; ++i){
    // ---- attention pipeline, NCH chunks of CB batches (16 pairs each) ----
    for (int c = 0; c < NCH; ++c){
      // QKV projection for this chunk: x rows [c*2048, +2048) @ W^T
      GP p{};
      p.AsMHi = (long)1024 * EE; p.AsMLo = EE; p.AsH = 0;
      p.BsNHi = (long)EE * EE;   p.BsNLo = EE; p.BsH = 0;
      p.Abatch = 0; p.Bbatch = (long)(2 * nWh); p.Obatch = (long)nChQ;
      p.BiasB = (long)HH * EE;
      p.OsMHi = (long)HH * SS * EE; p.OsMLo = EE;   // m = b_local*1024 + s
      p.OsNHi = (long)SS * EE; p.OsNLo = 1;         // n = h*512 + e
      p.M = CB * SS; p.N = HH * EE; p.K = EE;
      p.A = xb + (size_t)c * CB * SS * EE;
      p.B = wqb + (size_t)i * nWh;
      p.bias = qkvbias + (size_t)i * 3 * HH * EE;
      p.out = qc; p.scale = 1.f; p.causal = 0; p.resid = nullptr; p.Kpart = 0;
      gemm_launch(1, p, 3, stream);

      k_transpose<<<dim3(128, PAIRS), 256, 0, stream>>>(vc, vtc);

      GP ps{};
      ps.A = qc; ps.B = kc; ps.out = sc;
      ps.AsMHi = 0; ps.AsMLo = EE; ps.AsH = 0;
      ps.BsNHi = (long)512 * EE; ps.BsNLo = EE; ps.BsH = 0;
      ps.Abatch = (long)SS * EE; ps.Bbatch = (long)SS * EE;
      ps.Obatch = (long)SS * SS; ps.BiasB = 0;
      ps.OsMHi = 0; ps.OsMLo = SS; ps.OsNHi = 512; ps.OsNLo = 1;
      ps.M = SS; ps.N = SS; ps.K = EE;
      ps.scale = 0.044194173824159216f; ps.causal = 1;
      ps.bias = nullptr; ps.resid = nullptr; ps.Kpart = 0;
      gemm_launch(0, ps, PAIRS, stream);

      k_softmax<<<dim3(PAIRS * SS / 2), 256, 0, stream>>>(sc, alph);

      GP pv{};
      pv.A = sc; pv.B = vtc; pv.out = ao + (size_t)c * nChQ;
      pv.AsMHi = 0; pv.AsMLo = SS; pv.AsH = 512;
      pv.BsNHi = 0; pv.BsNLo = SS; pv.BsH = 512;
      pv.Abatch = (long)SS * SS; pv.Bbatch = (long)EE * SS;
      pv.Obatch = (long)SS * EE; pv.BiasB = 0;
      pv.OsMHi = 0; pv.OsMLo = EE; pv.OsNHi = 0; pv.OsNLo = 1;
      pv.M = SS; pv.N = EE; pv.K = SS; pv.causal = 1;
      pv.scale = 1.f; pv.bias = nullptr; pv.resid = nullptr; pv.Kpart = 0;
      gemm_launch(2, pv, PAIRS, stream);
    }

    // ---- attn_out: split-K x4 + fused reduce+bias+resid+LN1 ----
    GP pw{};
    pw.A = ao; pw.B = wob + (size_t)i * nWh; pw.out = parts;
    pw.AsMHi = (long)HH * SS * EE; pw.AsMLo = EE; pw.AsH = (long)SS * EE;
    pw.BsNHi = 0; pw.BsNLo = EE; pw.BsH = (long)EE * EE;
    pw.Abatch = pw.Bbatch = 0; pw.Obatch = (long)nX; pw.BiasB = 0;
    pw.OsMHi = (long)1024 * EE; pw.OsMLo = EE; pw.OsNHi = 0; pw.OsNLo = 1;
    pw.M = BB * SS; pw.N = EE; pw.K = HH * EE; pw.Kpart = (HH * EE) / 4;
    pw.bias = nullptr; pw.resid = nullptr; pw.scale = 1.f; pw.causal = 0;
    gemm_launch(5, pw, 4, stream);
    k_redln<<<dim3(BB * SS), 128, 0, stream>>>(parts, bo_sum + (size_t)i * EE, xf,
                                               ln1g + (size_t)i * EE,
                                               ln1b + (size_t)i * EE, xf, xb);

    // ---- FFN up: relu(x @ W1^T + b1) -> hid bf16 (aliases sc) ----
    GP p1{};
    p1.A = xb; p1.B = w1b + (size_t)i * nWf; p1.out = hid;
    p1.AsMHi = (long)1024 * EE; p1.AsMLo = EE; p1.AsH = 0;
    p1.BsNHi = (long)512 * EE; p1.BsNLo = EE; p1.BsH = 0;
    p1.Abatch = p1.Bbatch = p1.Obatch = 0; p1.BiasB = 0;
    p1.OsMHi = (long)1024 * FFD; p1.OsMLo = FFD; p1.OsNHi = 512; p1.OsNLo = 1;
    p1.M = BB * SS; p1.N = FFD; p1.K = EE;
    p1.bias = b1 + (size_t)i * FFD; p1.resid = nullptr; p1.scale = 1.f;
    p1.causal = 0; p1.Kpart = 0;
    gemm_launch(4, p1, 1, stream);

    // ---- FFN down: split-K x4 + fused reduce+bias+resid+LN2 ----
    GP p2{};
    p2.A = hid; p2.B = w2b + (size_t)i * nWf; p2.out = parts;
    p2.AsMHi = (long)1024 * FFD; p2.AsMLo = FFD; p2.AsH = 512;
    p2.BsNHi = 0; p2.BsNLo = FFD; p2.BsH = 512;
    p2.Abatch = p2.Bbatch = 0; p2.Obatch = (long)nX; p2.BiasB = 0;
    p2.OsMHi = (long)1024 * EE; p2.OsMLo = EE; p2.OsNHi = 0; p2.OsNLo = 1;
    p2.M = BB * SS; p2.N = EE; p2.K = FFD; p2.Kpart = FFD / 4;
    p2.bias = nullptr; p2.resid = nullptr; p2.scale = 1.f; p2.causal = 0;
    gemm_launch(5, p2, 4, stream);
    float* fdst = (i == LL - 1) ? out : xf;
    k_redln<<<dim3(BB * SS), 128, 0, stream>>>(parts, b2 + (size_t)i * EE, xf,
                                               ln2g + (size_t)i * EE,
                                               ln2b + (size_t)i * EE, fdst, xb);
  }
}

// Round 12
// 1229.383 us; speedup vs baseline: 2.6598x; 1.0206x over previous
//
#include <hip/hip_runtime.h>
#include <hip/hip_bf16.h>
#include <stdint.h>

#define LL 2
#define HH 8
#define EE 512
#define FFD 2048
#define BB 8
#define SS 1024
#define CB 2            // batches per attention chunk
#define NCH (BB / CB)   // 4 chunks
#define PAIRS (CB * HH) // 16 (b,h) pairs per chunk

typedef unsigned short u16;
typedef __attribute__((ext_vector_type(8))) short bf16x8;
typedef __attribute__((ext_vector_type(4))) float f32x4;
typedef __attribute__((ext_vector_type(4))) int int4v;
typedef __attribute__((ext_vector_type(2))) int int2v;

__device__ __forceinline__ u16 f2bf(float f){
  union { float f; unsigned u; } c; c.f = f;
  unsigned r = (c.u + 0x7FFFu + ((c.u >> 16) & 1u)) >> 16;
  return (u16)r;
}

// ---------------------------------------------------------------------------
// 128x128 tile GEMM, C = A(MxK) * B(NxK)^T, bf16 in / f32 accum.
// Round-2-best schedule (measured fastest): single 32KB LDS, __syncthreads
// pair per K-step, global_load_lds width=16, linear LDS dest, pre-swizzled
// global source, swizzled ds_read. No inline asm (m141 lesson).
// EP: 0=bf16 out*scale (+causal tile skip), 1=bf16 out+bias (bias+BiasB*bb),
// 2=bf16 out (+causal K-limit), 4=bf16 out+bias+relu, 5=f32 raw partial
// (split-K: blockIdx.y=part, K range [part*Kpart,+Kpart), out+=part*Obatch)
// ---------------------------------------------------------------------------
struct GP {
  const u16* A; const u16* B;
  const float* bias; const float* resid;
  void* out;
  long AsMHi, AsMLo, AsH;
  long BsNHi, BsNLo, BsH;
  long Abatch, Bbatch, Obatch, BiasB;
  long OsMHi, OsMLo, OsNHi, OsNLo;
  int M, N, K, causal, Kpart;
  float scale;
};

__device__ __forceinline__ int xcd_swz(int bid, int nwg){
  if (nwg < 16) return bid;
  const int q = nwg >> 3, r = nwg & 7;
  const int xcd = bid & 7, loc = bid >> 3;
  return (xcd < r ? xcd * (q + 1) : r * (q + 1) + (xcd - r) * q) + loc;
}

template<int EP>
__global__ __launch_bounds__(256, 3) void k_gemm(GP p){
  const int tilesN = p.N >> 7;
  const int bid = xcd_swz(blockIdx.x, gridDim.x);
  const int m0 = (bid / tilesN) << 7;
  const int n0 = (bid % tilesN) << 7;
  if (EP == 0 && p.causal && n0 > m0) return;   // fully-masked causal tile
  const long bb = blockIdx.y;
  const u16* __restrict__ Ag = p.A + bb * p.Abatch;
  const u16* __restrict__ Bg = p.B + bb * p.Bbatch;

  __shared__ __align__(16) u16 As[128 * 64];
  __shared__ __align__(16) u16 Bs[128 * 64];
  char* AsB = (char*)As;
  char* BsB = (char*)Bs;

  const int t = threadIdx.x;
  const int lane = t & 63;
  const int wv = t >> 6;
  const int wr = (wv >> 1) << 6;   // wave row origin (0/64)
  const int wc = (wv & 1) << 6;    // wave col origin (0/64)

  // staging geometry: wave wv, instr j -> LDS rows (wv*4+j)*8 .. +8
  // lane -> row +(lane>>3), 16B slot (lane&7). Global k pre-XORed so that
  // LDS byte c of row r holds global slab byte c ^ ((r&7)<<4).
  long aoff[4], boff[4];
  #pragma unroll
  for (int j = 0; j < 4; ++j){
    const int r = ((wv << 2) + j) * 8 + (lane >> 3);
    const int kx = ((lane & 7) << 3) ^ ((r & 7) << 3);
    const int gm = m0 + r;
    aoff[j] = (long)(gm >> 10) * p.AsMHi + (long)(gm & 1023) * p.AsMLo + kx;
    const int gn = n0 + r;
    boff[j] = (long)(gn >> 9) * p.BsNHi + (long)(gn & 511) * p.BsNLo + kx;
  }

  int kBeg = 0;
  int Klim = p.K;
  if (EP == 2 && p.causal) { int kl = m0 + 128; Klim = kl < p.K ? kl : p.K; }
  if (EP == 5) { kBeg = (int)bb * p.Kpart; Klim = kBeg + p.Kpart; }

  f32x4 acc[4][4];
  #pragma unroll
  for (int a = 0; a < 4; ++a)
    #pragma unroll
    for (int b = 0; b < 4; ++b)
      acc[a][b] = (f32x4){0.f, 0.f, 0.f, 0.f};

  for (int k0 = kBeg; k0 < Klim; k0 += 64){
    const long ka = (long)(k0 >> 9) * p.AsH + (k0 & 511);
    const long kb = (long)(k0 >> 9) * p.BsH + (k0 & 511);
    __syncthreads();   // LDS free (previous MFMA phase done)
    #pragma unroll
    for (int j = 0; j < 4; ++j){
      const int ldsOff = (((wv << 2) + j) << 9);   // u16 elems, 1KB per instr
      __builtin_amdgcn_global_load_lds(
          (const __attribute__((address_space(1))) void*)(Ag + aoff[j] + ka),
          (__attribute__((address_space(3))) void*)(As + ldsOff), 16, 0, 0);
      __builtin_amdgcn_global_load_lds(
          (const __attribute__((address_space(1))) void*)(Bg + boff[j] + kb),
          (__attribute__((address_space(3))) void*)(Bs + ldsOff), 16, 0, 0);
    }
    __syncthreads();   // tile resident
    #pragma unroll
    for (int kk = 0; kk < 2; ++kk){
      bf16x8 af[4], bv[4];
      #pragma unroll
      for (int mi = 0; mi < 4; ++mi){
        int row = wr + (mi << 4) + (lane & 15);
        int bc = ((kk << 6) + ((lane >> 4) << 4)) ^ ((row & 7) << 4);
        af[mi] = *reinterpret_cast<const bf16x8*>(AsB + row * 128 + bc);
      }
      #pragma unroll
      for (int ni = 0; ni < 4; ++ni){
        int row = wc + (ni << 4) + (lane & 15);
        int bc = ((kk << 6) + ((lane >> 4) << 4)) ^ ((row & 7) << 4);
        bv[ni] = *reinterpret_cast<const bf16x8*>(BsB + row * 128 + bc);
      }
      #pragma unroll
      for (int mi = 0; mi < 4; ++mi)
        #pragma unroll
        for (int ni = 0; ni < 4; ++ni)
          acc[mi][ni] = __builtin_amdgcn_mfma_f32_16x16x32_bf16(af[mi], bv[ni], acc[mi][ni], 0, 0, 0);
    }
  }

  // epilogue: D row=(lane>>4)*4+i, col=lane&15
  const int cm = (lane >> 4) << 2;
  const int cn = lane & 15;
  float biasv[4];
  if (EP == 1 || EP == 4){
    #pragma unroll
    for (int ni = 0; ni < 4; ++ni)
      biasv[ni] = p.bias[bb * p.BiasB + n0 + wc + (ni << 4) + cn];
  }
  #pragma unroll
  for (int mi = 0; mi < 4; ++mi){
    #pragma unroll
    for (int i = 0; i < 4; ++i){
      const int m = m0 + wr + (mi << 4) + cm + i;
      const long ob = bb * p.Obatch + (long)(m >> 10) * p.OsMHi + (long)(m & 1023) * p.OsMLo;
      #pragma unroll
      for (int ni = 0; ni < 4; ++ni){
        const int n = n0 + wc + (ni << 4) + cn;
        const long oa = ob + (long)(n >> 9) * p.OsNHi + (long)(n & 511) * p.OsNLo;
        float v = acc[mi][ni][i];
        if (EP == 0) ((u16*)p.out)[oa] = f2bf(v * p.scale);
        else if (EP == 1) ((u16*)p.out)[oa] = f2bf(v + biasv[ni]);
        else if (EP == 2) ((u16*)p.out)[oa] = f2bf(v);
        else if (EP == 5) ((float*)p.out)[oa] = v;
        else { float r = v + biasv[ni]; ((u16*)p.out)[oa] = f2bf(r > 0.f ? r : 0.f); }
      }
    }
  }
}

// ---------------------------------------------------------------------------
// Fused: sum 4 split-K partials + bias + resid -> LayerNorm -> f32 + bf16 out.
__global__ __launch_bounds__(128) void k_redln(const float* __restrict__ part,
                                               const float* __restrict__ bias,
                                               const float* __restrict__ resid,
                                               const float* __restrict__ g,
                                               const float* __restrict__ b,
                                               float* __restrict__ fdst,
                                               u16* __restrict__ bdst){
  const long row = blockIdx.x;
  const int t = threadIdx.x;
  const int col = t << 2;
  const long off = row * EE + col;
  const long nX = (long)BB * SS * EE;
  f32x4 s = *reinterpret_cast<const f32x4*>(part + off);
  #pragma unroll
  for (int q = 1; q < 4; ++q){
    f32x4 v = *reinterpret_cast<const f32x4*>(part + q * nX + off);
    s.x += v.x; s.y += v.y; s.z += v.z; s.w += v.w;
  }
  f32x4 bv = *reinterpret_cast<const f32x4*>(bias + col);
  f32x4 rv = *reinterpret_cast<const f32x4*>(resid + off);
  s.x += bv.x + rv.x; s.y += bv.y + rv.y; s.z += bv.z + rv.z; s.w += bv.w + rv.w;

  float ps = s.x + s.y + s.z + s.w;
  #pragma unroll
  for (int o = 32; o; o >>= 1) ps += __shfl_xor(ps, o);
  __shared__ float red[2], red2[2];
  if ((t & 63) == 0) red[t >> 6] = ps;
  __syncthreads();
  const float mean = (red[0] + red[1]) * (1.0f / EE);
  f32x4 d = { s.x - mean, s.y - mean, s.z - mean, s.w - mean };
  float pv = d.x * d.x + d.y * d.y + d.z * d.z + d.w * d.w;
  #pragma unroll
  for (int o = 32; o; o >>= 1) pv += __shfl_xor(pv, o);
  if ((t & 63) == 0) red2[t >> 6] = pv;
  __syncthreads();
  const float var = (red2[0] + red2[1]) * (1.0f / EE);
  const float rstd = rsqrtf(var + 1e-5f);
  f32x4 gv = *reinterpret_cast<const f32x4*>(g + col);
  f32x4 bb = *reinterpret_cast<const f32x4*>(b + col);
  f32x4 o4 = { d.x * rstd * gv.x + bb.x, d.y * rstd * gv.y + bb.y,
               d.z * rstd * gv.z + bb.z, d.w * rstd * gv.w + bb.w };
  *reinterpret_cast<f32x4*>(fdst + off) = o4;
  union { u16 us[4]; int2v v; } u;
  u.us[0] = f2bf(o4.x); u.us[1] = f2bf(o4.y);
  u.us[2] = f2bf(o4.z); u.us[3] = f2bf(o4.w);
  *reinterpret_cast<int2v*>(bdst + off) = u.v;
}

// ---------------------------------------------------------------------------
// ONE-SHOT setup dispatch: x->xf,xb cast; ALL weight f32->bf16 (dst buffers
// are contiguous from wdst); per-layer [bq|bk|bv] concat + bo_sum.
struct SetupP {
  const float *x, *Wq, *Wk, *Wv, *Wo, *W1, *W2, *bq, *bk, *bv, *bo;
  float *xf, *catb, *bos;
  u16 *xb, *wdst;
};
#define SETUP_TA 524288u            // nX/8 threads for x
#define SETUP_TB 2621440u           // (8*nWh + 4*nWf)/8 threads for weights
#define SETUP_TC 25600u             // bias prep threads
__global__ __launch_bounds__(256) void k_setup(SetupP sp){
  const unsigned t = blockIdx.x * 256 + threadIdx.x;
  if (t < SETUP_TA){
    const int i = (int)t << 3;
    f32x4 a = *reinterpret_cast<const f32x4*>(sp.x + i);
    f32x4 b = *reinterpret_cast<const f32x4*>(sp.x + i + 4);
    *reinterpret_cast<f32x4*>(sp.xf + i) = a;
    *reinterpret_cast<f32x4*>(sp.xf + i + 4) = b;
    union { u16 us[8]; int4v v; } u;
    #pragma unroll
    for (int j = 0; j < 4; ++j){ u.us[j] = f2bf(a[j]); u.us[4 + j] = f2bf(b[j]); }
    *reinterpret_cast<int4v*>(sp.xb + i) = u.v;
  } else if (t < SETUP_TA + SETUP_TB){
    const size_t j = ((size_t)(t - SETUP_TA)) << 3;   // dst elem index
    const size_t R = (size_t)4194304;                 // 2*nWh (elems/region Wq..Wo)
    const size_t F = (size_t)2097152;                 // 2*nWf
    const float* src;
    size_t loc;
    if      (j < R)         { src = sp.Wq; loc = j; }
    else if (j < 2*R)       { src = sp.Wk; loc = j - R; }
    else if (j < 3*R)       { src = sp.Wv; loc = j - 2*R; }
    else if (j < 4*R)       { src = sp.Wo; loc = j - 3*R; }
    else if (j < 4*R + F)   { src = sp.W1; loc = j - 4*R; }
    else                    { src = sp.W2; loc = j - 4*R - F; }
    f32x4 a = *reinterpret_cast<const f32x4*>(src + loc);
    f32x4 b = *reinterpret_cast<const f32x4*>(src + loc + 4);
    union { u16 us[8]; int4v v; } u;
    #pragma unroll
    for (int q = 0; q < 4; ++q){ u.us[q] = f2bf(a[q]); u.us[4 + q] = f2bf(b[q]); }
    *reinterpret_cast<int4v*>(sp.wdst + j) = u.v;
  } else {
    const int j = (int)(t - SETUP_TA - SETUP_TB);
    if (j >= 2 * 12800) return;
    const int L = j / 12800;
    const int r = j - L * 12800;
    const int lw = L * HH * EE;
    float* catL = sp.catb + (size_t)L * 3 * HH * EE;
    if (r < 4096) catL[r] = sp.bq[lw + r];
    else if (r < 8192) catL[r] = sp.bk[lw + r - 4096];
    else if (r < 12288) catL[r] = sp.bv[lw + r - 8192];
    else {
      const int o = r - 12288;
      float s = 0.f;
      #pragma unroll
      for (int h = 0; h < HH; ++h) s += sp.bo[lw + h * EE + o];
      sp.bos[L * EE + o] = s;
    }
  }
}

// ---------------------------------------------------------------------------
// Barrier-free row softmax: one WAVE per row (4 rows / 256-thr block).
// In-place on bf16 scores; masked tail zero-filled up to the 128-aligned
// causal limit (PV never reads beyond it); second half [512,1024) touched
// only when q >= 512. P *= alpha[h].
__global__ __launch_bounds__(256) void k_softmax(u16* __restrict__ sp,
                                                 const float* __restrict__ alphas){
  const int wv = threadIdx.x >> 6;             // wave = row within block
  const long row = (long)blockIdx.x * 4 + wv;
  const int lane = threadIdx.x & 63;
  const int q = (int)(row & (SS - 1));
  const int h = (int)(row >> 10) & (HH - 1);
  const bool half2 = q >= 512;                 // limit > 512 iff q >= 512
  u16* rp = sp + row * SS;
  const int i0 = lane << 3;                    // 0..504
  float v[8], v2[8];
  float lm = -1e30f;
  {
    bf16x8 a = *reinterpret_cast<const bf16x8*>(rp + i0);
    #pragma unroll
    for (int j = 0; j < 8; ++j){
      union { unsigned u; float f; } c; c.u = ((unsigned)(u16)a[j]) << 16;
      v[j] = (i0 + j <= q) ? c.f : -1e30f;
      lm = fmaxf(lm, v[j]);
    }
  }
  if (half2){
    bf16x8 a = *reinterpret_cast<const bf16x8*>(rp + i0 + 512);
    #pragma unroll
    for (int j = 0; j < 8; ++j){
      union { unsigned u; float f; } c; c.u = ((unsigned)(u16)a[j]) << 16;
      v2[j] = (i0 + 512 + j <= q) ? c.f : -1e30f;
      lm = fmaxf(lm, v2[j]);
    }
  }
  #pragma unroll
  for (int o = 32; o; o >>= 1) lm = fmaxf(lm, __shfl_xor(lm, o));
  float ls = 0.f;
  #pragma unroll
  for (int j = 0; j < 8; ++j){
    float e = exp2f((v[j] - lm) * 1.4426950408889634f);
    e = (i0 + j <= q) ? e : 0.f;
    v[j] = e; ls += e;
  }
  if (half2){
    #pragma unroll
    for (int j = 0; j < 8; ++j){
      float e = exp2f((v2[j] - lm) * 1.4426950408889634f);
      e = (i0 + 512 + j <= q) ? e : 0.f;
      v2[j] = e; ls += e;
    }
  }
  #pragma unroll
  for (int o = 32; o; o >>= 1) ls += __shfl_xor(ls, o);
  const float inv = alphas[h] / ls;
  {
    union { u16 us[8]; bf16x8 v8; } o8;
    #pragma unroll
    for (int j = 0; j < 8; ++j) o8.us[j] = f2bf(v[j] * inv);
    *reinterpret_cast<bf16x8*>(rp + i0) = o8.v8;
  }
  if (half2){
    union { u16 us[8]; bf16x8 v8; } o8;
    #pragma unroll
    for (int j = 0; j < 8; ++j) o8.us[j] = f2bf(v2[j] * inv);
    *reinterpret_cast<bf16x8*>(rp + i0 + 512) = o8.v8;
  }
}

// per-pair (S,E) -> (E,S), 64x64 bf16 tiles; blockIdx.y = local pair
__global__ __launch_bounds__(256) void k_transpose(const u16* __restrict__ v,
                                                   u16* __restrict__ vt){
  const long bh = blockIdx.y;
  const int ts = blockIdx.x >> 3;
  const int td = blockIdx.x & 7;
  const u16* src = v + bh * (long)(SS * EE) + (long)(ts * 64) * EE + td * 64;
  u16* dst = vt + bh * (long)(SS * EE) + (long)(td * 64) * SS + ts * 64;
  __shared__ __align__(16) u16 tl[64][80];
  const int t = threadIdx.x;
  #pragma unroll
  for (int it = 0; it < 2; ++it){
    int id = t + it * 256;
    int r = id >> 3, c = (id & 7) << 3;
    *reinterpret_cast<int4v*>(&tl[r][c]) =
        *reinterpret_cast<const int4v*>(src + (long)r * EE + c);
  }
  __syncthreads();
  #pragma unroll
  for (int it = 0; it < 2; ++it){
    int id = t + it * 256;
    int r = id >> 3, c = (id & 7) << 3;
    union { u16 us[8]; int4v v; } u;
    #pragma unroll
    for (int j = 0; j < 8; ++j) u.us[j] = tl[c + j][r];
    *reinterpret_cast<int4v*>(dst + (long)r * SS + c) = u.v;
  }
}

// ---------------------------------------------------------------------------
static inline void gemm_launch(int EP, const GP& p, int batch, hipStream_t st){
  dim3 g((unsigned)((p.M >> 7) * (p.N >> 7)), (unsigned)batch);
  switch (EP){
    case 0: k_gemm<0><<<g, 256, 0, st>>>(p); break;
    case 1: k_gemm<1><<<g, 256, 0, st>>>(p); break;
    case 2: k_gemm<2><<<g, 256, 0, st>>>(p); break;
    case 4: k_gemm<4><<<g, 256, 0, st>>>(p); break;
    case 5: k_gemm<5><<<g, 256, 0, st>>>(p); break;
  }
}

extern "C" void kernel_launch(void* const* d_in, const int* in_sizes, int n_in,
                              void* d_out, int out_size, void* d_ws, size_t ws_size,
                              hipStream_t stream){
  const float* x    = (const float*)d_in[0];
  const float* Wq   = (const float*)d_in[1];
  const float* bq   = (const float*)d_in[2];
  const float* Wk   = (const float*)d_in[3];
  const float* bk   = (const float*)d_in[4];
  const float* Wv   = (const float*)d_in[5];
  const float* bv   = (const float*)d_in[6];
  const float* Wo   = (const float*)d_in[7];
  const float* bo   = (const float*)d_in[8];
  const float* alph = (const float*)d_in[9];
  const float* ln1g = (const float*)d_in[10];
  const float* ln1b = (const float*)d_in[11];
  const float* W1   = (const float*)d_in[12];
  const float* b1   = (const float*)d_in[13];
  const float* W2   = (const float*)d_in[14];
  const float* b2   = (const float*)d_in[15];
  const float* ln2g = (const float*)d_in[16];
  const float* ln2b = (const float*)d_in[17];
  float* out = (float*)d_out;

  const size_t nWh = (size_t)HH * EE * EE;           // 2,097,152
  const size_t nWf = (size_t)FFD * EE;               // 1,048,576
  const size_t nX  = (size_t)BB * SS * EE;           // 4,194,304
  const size_t nQ  = (size_t)BB * HH * SS * EE;      // 33,554,432
  const size_t nChQ = (size_t)CB * HH * SS * EE;     // 8,388,608 per chunk buf
  const size_t nScC = (size_t)PAIRS * SS * SS;       // 16,777,216 scores/chunk

  char* w = (char*)d_ws;
  size_t off = 0;
  auto take = [&](size_t bytes) -> char* {
    char* p = w + off;
    off += (bytes + 255) & ~(size_t)255;
    return p;
  };

  // weight buffers hold BOTH layers [L0|L1]; all six are CONTIGUOUS (each
  // size 256B-divisible) -> k_setup writes them as one run from wqb.
  u16* wqb = (u16*)take(4 * nWh);
  u16* wkb = (u16*)take(4 * nWh);
  u16* wvb = (u16*)take(4 * nWh);
  u16* wob = (u16*)take(4 * nWh);
  u16* w1b = (u16*)take(4 * nWf);
  u16* w2b = (u16*)take(4 * nWf);
  float* xf = (float*)take(4 * nX);
  u16* xb   = (u16*)take(2 * nX);
  u16* ao   = (u16*)take(2 * nQ);     // PV output, (B,H,S,E) bf16
  u16* qc   = (u16*)take(2 * nChQ);   // per-chunk Q/K/V/Vt — contiguous
  u16* kc   = (u16*)take(2 * nChQ);
  u16* vc   = (u16*)take(2 * nChQ);
  u16* vtc  = (u16*)take(2 * nChQ);
  u16* sc   = (u16*)take(2 * nScC);   // per-chunk bf16 scores (in-place P)
  float* bo_sum  = (float*)take(4 * 2 * EE);
  float* qkvbias = (float*)take(4 * 2 * 3 * HH * EE);
  // split-K partials: 4 x nX f32 = 67,108,864 B = exactly the qc..vtc span
  // (dead during Wo and FFN2 — attention fully consumed them into ao).
  float* parts = (float*)qc;
  // FFN hidden: 8192x2048 bf16 = 33,554,432 B = exactly sc (dead after PV).
  u16* hid = sc;

  // ---- ONE setup dispatch: input cast + all weight cvt + bias prep ----
  SetupP spp{ x, Wq, Wk, Wv, Wo, W1, W2, bq, bk, bv, bo,
              xf, qkvbias, bo_sum, xb, wqb };
  k_setup<<<dim3((SETUP_TA + SETUP_TB + SETUP_TC) / 256), 256, 0, stream>>>(spp);

  for (int i = 0; i < LL; ++i){
    // ---- attention pipeline, NCH chunks of CB batches (16 pairs each) ----
    for (int c = 0; c < NCH; ++c){
      // QKV projection for this chunk: x rows [c*2048, +2048) @ W^T
      GP p{};
      p.AsMHi = (long)1024 * EE; p.AsMLo = EE; p.AsH = 0;
      p.BsNHi = (long)EE * EE;   p.BsNLo = EE; p.BsH = 0;
      p.Abatch = 0; p.Bbatch = (long)(2 * nWh); p.Obatch = (long)nChQ;
      p.BiasB = (long)HH * EE;
      p.OsMHi = (long)HH * SS * EE; p.OsMLo = EE;   // m = b_local*1024 + s
      p.OsNHi = (long)SS * EE; p.OsNLo = 1;         // n = h*512 + e
      p.M = CB * SS; p.N = HH * EE; p.K = EE;
      p.A = xb + (size_t)c * CB * SS * EE;
      p.B = wqb + (size_t)i * nWh;
      p.bias = qkvbias + (size_t)i * 3 * HH * EE;
      p.out = qc; p.scale = 1.f; p.causal = 0; p.resid = nullptr; p.Kpart = 0;
      gemm_launch(1, p, 3, stream);

      k_transpose<<<dim3(128, PAIRS), 256, 0, stream>>>(vc, vtc);

      GP ps{};
      ps.A = qc; ps.B = kc; ps.out = sc;
      ps.AsMHi = 0; ps.AsMLo = EE; ps.AsH = 0;
      ps.BsNHi = (long)512 * EE; ps.BsNLo = EE; ps.BsH = 0;
      ps.Abatch = (long)SS * EE; ps.Bbatch = (long)SS * EE;
      ps.Obatch = (long)SS * SS; ps.BiasB = 0;
      ps.OsMHi = 0; ps.OsMLo = SS; ps.OsNHi = 512; ps.OsNLo = 1;
      ps.M = SS; ps.N = SS; ps.K = EE;
      ps.scale = 0.044194173824159216f; ps.causal = 1;
      ps.bias = nullptr; ps.resid = nullptr; ps.Kpart = 0;
      gemm_launch(0, ps, PAIRS, stream);

      k_softmax<<<dim3(PAIRS * SS / 4), 256, 0, stream>>>(sc, alph);

      GP pv{};
      pv.A = sc; pv.B = vtc; pv.out = ao + (size_t)c * nChQ;
      pv.AsMHi = 0; pv.AsMLo = SS; pv.AsH = 512;
      pv.BsNHi = 0; pv.BsNLo = SS; pv.BsH = 512;
      pv.Abatch = (long)SS * SS; pv.Bbatch = (long)EE * SS;
      pv.Obatch = (long)SS * EE; pv.BiasB = 0;
      pv.OsMHi = 0; pv.OsMLo = EE; pv.OsNHi = 0; pv.OsNLo = 1;
      pv.M = SS; pv.N = EE; pv.K = SS; pv.causal = 1;
      pv.scale = 1.f; pv.bias = nullptr; pv.resid = nullptr; pv.Kpart = 0;
      gemm_launch(2, pv, PAIRS, stream);
    }

    // ---- attn_out: split-K x4 + fused reduce+bias+resid+LN1 ----
    GP pw{};
    pw.A = ao; pw.B = wob + (size_t)i * nWh; pw.out = parts;
    pw.AsMHi = (long)HH * SS * EE; pw.AsMLo = EE; pw.AsH = (long)SS * EE;
    pw.BsNHi = 0; pw.BsNLo = EE; pw.BsH = (long)EE * EE;
    pw.Abatch = pw.Bbatch = 0; pw.Obatch = (long)nX; pw.BiasB = 0;
    pw.OsMHi = (long)1024 * EE; pw.OsMLo = EE; pw.OsNHi = 0; pw.OsNLo = 1;
    pw.M = BB * SS; pw.N = EE; pw.K = HH * EE; pw.Kpart = (HH * EE) / 4;
    pw.bias = nullptr; pw.resid = nullptr; pw.scale = 1.f; pw.causal = 0;
    gemm_launch(5, pw, 4, stream);
    k_redln<<<dim3(BB * SS), 128, 0, stream>>>(parts, bo_sum + (size_t)i * EE, xf,
                                               ln1g + (size_t)i * EE,
                                               ln1b + (size_t)i * EE, xf, xb);

    // ---- FFN up: relu(x @ W1^T + b1) -> hid bf16 (aliases sc) ----
    GP p1{};
    p1.A = xb; p1.B = w1b + (size_t)i * nWf; p1.out = hid;
    p1.AsMHi = (long)1024 * EE; p1.AsMLo = EE; p1.AsH = 0;
    p1.BsNHi = (long)512 * EE; p1.BsNLo = EE; p1.BsH = 0;
    p1.Abatch = p1.Bbatch = p1.Obatch = 0; p1.BiasB = 0;
    p1.OsMHi = (long)1024 * FFD; p1.OsMLo = FFD; p1.OsNHi = 512; p1.OsNLo = 1;
    p1.M = BB * SS; p1.N = FFD; p1.K = EE;
    p1.bias = b1 + (size_t)i * FFD; p1.resid = nullptr; p1.scale = 1.f;
    p1.causal = 0; p1.Kpart = 0;
    gemm_launch(4, p1, 1, stream);

    // ---- FFN down: split-K x4 + fused reduce+bias+resid+LN2 ----
    GP p2{};
    p2.A = hid; p2.B = w2b + (size_t)i * nWf; p2.out = parts;
    p2.AsMHi = (long)1024 * FFD; p2.AsMLo = FFD; p2.AsH = 512;
    p2.BsNHi = 0; p2.BsNLo = FFD; p2.BsH = 512;
    p2.Abatch = p2.Bbatch = 0; p2.Obatch = (long)nX; p2.BiasB = 0;
    p2.OsMHi = (long)1024 * EE; p2.OsMLo = EE; p2.OsNHi = 0; p2.OsNLo = 1;
    p2.M = BB * SS; p2.N = EE; p2.K = FFD; p2.Kpart = FFD / 4;
    p2.bias = nullptr; p2.resid = nullptr; p2.scale = 1.f; p2.causal = 0;
    gemm_launch(5, p2, 4, stream);
    float* fdst = (i == LL - 1) ? out : xf;
    k_redln<<<dim3(BB * SS), 128, 0, stream>>>(parts, b2 + (size_t)i * EE, xf,
                                               ln2g + (size_t)i * EE,
                                               ln2b + (size_t)i * EE, fdst, xb);
  }
}

// Round 13
// 1122.105 us; speedup vs baseline: 2.9141x; 1.0956x over previous
//
#include <hip/hip_runtime.h>
#include <hip/hip_bf16.h>
#include <stdint.h>

#define LL 2
#define HH 8
#define EE 512
#define FFD 2048
#define BB 8
#define SS 1024
#define CB 4            // batches per attention chunk
#define NCH (BB / CB)   // 2 chunks
#define PAIRS (CB * HH) // 32 (b,h) pairs per chunk

typedef unsigned short u16;
typedef __attribute__((ext_vector_type(8))) short bf16x8;
typedef __attribute__((ext_vector_type(4))) float f32x4;
typedef __attribute__((ext_vector_type(4))) int int4v;
typedef __attribute__((ext_vector_type(2))) int int2v;

__device__ __forceinline__ u16 f2bf(float f){
  union { float f; unsigned u; } c; c.f = f;
  unsigned r = (c.u + 0x7FFFu + ((c.u >> 16) & 1u)) >> 16;
  return (u16)r;
}

// ---------------------------------------------------------------------------
// 128x128 tile GEMM, C = A(MxK) * B(NxK)^T, bf16 in / f32 accum.
// Round-2-best schedule (measured fastest): single 32KB LDS, __syncthreads
// pair per K-step, global_load_lds width=16, linear LDS dest, pre-swizzled
// global source, swizzled ds_read. No inline asm (m141 lesson).
// EP: 0=bf16 out*scale (+causal tile skip), 1=bf16 out+bias (bias+BiasB*bb),
// 2=bf16 out (+causal K-limit), 4=bf16 out+bias+relu, 5=f32 raw partial
// (split-K: blockIdx.y=part, K range [part*Kpart,+Kpart), out+=part*Obatch)
// ---------------------------------------------------------------------------
struct GP {
  const u16* A; const u16* B;
  const float* bias; const float* resid;
  void* out;
  long AsMHi, AsMLo, AsH;
  long BsNHi, BsNLo, BsH;
  long Abatch, Bbatch, Obatch, BiasB;
  long OsMHi, OsMLo, OsNHi, OsNLo;
  int M, N, K, causal, Kpart;
  float scale;
};

__device__ __forceinline__ int xcd_swz(int bid, int nwg){
  if (nwg < 16) return bid;
  const int q = nwg >> 3, r = nwg & 7;
  const int xcd = bid & 7, loc = bid >> 3;
  return (xcd < r ? xcd * (q + 1) : r * (q + 1) + (xcd - r) * q) + loc;
}

template<int EP>
__global__ __launch_bounds__(256, 3) void k_gemm(GP p){
  const int tilesN = p.N >> 7;
  const int bid = xcd_swz(blockIdx.x, gridDim.x);
  const int m0 = (bid / tilesN) << 7;
  const int n0 = (bid % tilesN) << 7;
  if (EP == 0 && p.causal && n0 > m0) return;   // fully-masked causal tile
  const long bb = blockIdx.y;
  const u16* __restrict__ Ag = p.A + bb * p.Abatch;
  const u16* __restrict__ Bg = p.B + bb * p.Bbatch;

  __shared__ __align__(16) u16 As[128 * 64];
  __shared__ __align__(16) u16 Bs[128 * 64];
  char* AsB = (char*)As;
  char* BsB = (char*)Bs;

  const int t = threadIdx.x;
  const int lane = t & 63;
  const int wv = t >> 6;
  const int wr = (wv >> 1) << 6;   // wave row origin (0/64)
  const int wc = (wv & 1) << 6;    // wave col origin (0/64)

  // staging geometry: wave wv, instr j -> LDS rows (wv*4+j)*8 .. +8
  // lane -> row +(lane>>3), 16B slot (lane&7). Global k pre-XORed so that
  // LDS byte c of row r holds global slab byte c ^ ((r&7)<<4).
  long aoff[4], boff[4];
  #pragma unroll
  for (int j = 0; j < 4; ++j){
    const int r = ((wv << 2) + j) * 8 + (lane >> 3);
    const int kx = ((lane & 7) << 3) ^ ((r & 7) << 3);
    const int gm = m0 + r;
    aoff[j] = (long)(gm >> 10) * p.AsMHi + (long)(gm & 1023) * p.AsMLo + kx;
    const int gn = n0 + r;
    boff[j] = (long)(gn >> 9) * p.BsNHi + (long)(gn & 511) * p.BsNLo + kx;
  }

  int kBeg = 0;
  int Klim = p.K;
  if (EP == 2 && p.causal) { int kl = m0 + 128; Klim = kl < p.K ? kl : p.K; }
  if (EP == 5) { kBeg = (int)bb * p.Kpart; Klim = kBeg + p.Kpart; }

  f32x4 acc[4][4];
  #pragma unroll
  for (int a = 0; a < 4; ++a)
    #pragma unroll
    for (int b = 0; b < 4; ++b)
      acc[a][b] = (f32x4){0.f, 0.f, 0.f, 0.f};

  for (int k0 = kBeg; k0 < Klim; k0 += 64){
    const long ka = (long)(k0 >> 9) * p.AsH + (k0 & 511);
    const long kb = (long)(k0 >> 9) * p.BsH + (k0 & 511);
    __syncthreads();   // LDS free (previous MFMA phase done)
    #pragma unroll
    for (int j = 0; j < 4; ++j){
      const int ldsOff = (((wv << 2) + j) << 9);   // u16 elems, 1KB per instr
      __builtin_amdgcn_global_load_lds(
          (const __attribute__((address_space(1))) void*)(Ag + aoff[j] + ka),
          (__attribute__((address_space(3))) void*)(As + ldsOff), 16, 0, 0);
      __builtin_amdgcn_global_load_lds(
          (const __attribute__((address_space(1))) void*)(Bg + boff[j] + kb),
          (__attribute__((address_space(3))) void*)(Bs + ldsOff), 16, 0, 0);
    }
    __syncthreads();   // tile resident
    #pragma unroll
    for (int kk = 0; kk < 2; ++kk){
      bf16x8 af[4], bv[4];
      #pragma unroll
      for (int mi = 0; mi < 4; ++mi){
        int row = wr + (mi << 4) + (lane & 15);
        int bc = ((kk << 6) + ((lane >> 4) << 4)) ^ ((row & 7) << 4);
        af[mi] = *reinterpret_cast<const bf16x8*>(AsB + row * 128 + bc);
      }
      #pragma unroll
      for (int ni = 0; ni < 4; ++ni){
        int row = wc + (ni << 4) + (lane & 15);
        int bc = ((kk << 6) + ((lane >> 4) << 4)) ^ ((row & 7) << 4);
        bv[ni] = *reinterpret_cast<const bf16x8*>(BsB + row * 128 + bc);
      }
      #pragma unroll
      for (int mi = 0; mi < 4; ++mi)
        #pragma unroll
        for (int ni = 0; ni < 4; ++ni)
          acc[mi][ni] = __builtin_amdgcn_mfma_f32_16x16x32_bf16(af[mi], bv[ni], acc[mi][ni], 0, 0, 0);
    }
  }

  // epilogue: D row=(lane>>4)*4+i, col=lane&15
  const int cm = (lane >> 4) << 2;
  const int cn = lane & 15;
  float biasv[4];
  if (EP == 1 || EP == 4){
    #pragma unroll
    for (int ni = 0; ni < 4; ++ni)
      biasv[ni] = p.bias[bb * p.BiasB + n0 + wc + (ni << 4) + cn];
  }
  #pragma unroll
  for (int mi = 0; mi < 4; ++mi){
    #pragma unroll
    for (int i = 0; i < 4; ++i){
      const int m = m0 + wr + (mi << 4) + cm + i;
      const long ob = bb * p.Obatch + (long)(m >> 10) * p.OsMHi + (long)(m & 1023) * p.OsMLo;
      #pragma unroll
      for (int ni = 0; ni < 4; ++ni){
        const int n = n0 + wc + (ni << 4) + cn;
        const long oa = ob + (long)(n >> 9) * p.OsNHi + (long)(n & 511) * p.OsNLo;
        float v = acc[mi][ni][i];
        if (EP == 0) ((u16*)p.out)[oa] = f2bf(v * p.scale);
        else if (EP == 1) ((u16*)p.out)[oa] = f2bf(v + biasv[ni]);
        else if (EP == 2) ((u16*)p.out)[oa] = f2bf(v);
        else if (EP == 5) ((float*)p.out)[oa] = v;
        else { float r = v + biasv[ni]; ((u16*)p.out)[oa] = f2bf(r > 0.f ? r : 0.f); }
      }
    }
  }
}

// ---------------------------------------------------------------------------
// Fused: sum 4 split-K partials + bias + resid -> LayerNorm -> f32 + bf16 out.
// Rows [rowBase, rowBase+gridDim.x); partials are mn-strided (mn = M*N of the
// producing split-K GEMM, partial row 0 = rowBase's row).
__global__ __launch_bounds__(128) void k_redln(const float* __restrict__ part,
                                               const float* __restrict__ bias,
                                               const float* __restrict__ resid,
                                               const float* __restrict__ g,
                                               const float* __restrict__ b,
                                               float* __restrict__ fdst,
                                               u16* __restrict__ bdst,
                                               long rowBase, long mn){
  const long lrow = blockIdx.x;           // local row within chunk
  const long row = rowBase + lrow;
  const int t = threadIdx.x;
  const int col = t << 2;
  const long poff = lrow * EE + col;      // into partials
  const long off = row * EE + col;        // into resid/out
  f32x4 s = *reinterpret_cast<const f32x4*>(part + poff);
  #pragma unroll
  for (int q = 1; q < 4; ++q){
    f32x4 v = *reinterpret_cast<const f32x4*>(part + q * mn + poff);
    s.x += v.x; s.y += v.y; s.z += v.z; s.w += v.w;
  }
  f32x4 bv = *reinterpret_cast<const f32x4*>(bias + col);
  f32x4 rv = *reinterpret_cast<const f32x4*>(resid + off);
  s.x += bv.x + rv.x; s.y += bv.y + rv.y; s.z += bv.z + rv.z; s.w += bv.w + rv.w;

  float ps = s.x + s.y + s.z + s.w;
  #pragma unroll
  for (int o = 32; o; o >>= 1) ps += __shfl_xor(ps, o);
  __shared__ float red[2], red2[2];
  if ((t & 63) == 0) red[t >> 6] = ps;
  __syncthreads();
  const float mean = (red[0] + red[1]) * (1.0f / EE);
  f32x4 d = { s.x - mean, s.y - mean, s.z - mean, s.w - mean };
  float pv = d.x * d.x + d.y * d.y + d.z * d.z + d.w * d.w;
  #pragma unroll
  for (int o = 32; o; o >>= 1) pv += __shfl_xor(pv, o);
  if ((t & 63) == 0) red2[t >> 6] = pv;
  __syncthreads();
  const float var = (red2[0] + red2[1]) * (1.0f / EE);
  const float rstd = rsqrtf(var + 1e-5f);
  f32x4 gv = *reinterpret_cast<const f32x4*>(g + col);
  f32x4 bb = *reinterpret_cast<const f32x4*>(b + col);
  f32x4 o4 = { d.x * rstd * gv.x + bb.x, d.y * rstd * gv.y + bb.y,
               d.z * rstd * gv.z + bb.z, d.w * rstd * gv.w + bb.w };
  *reinterpret_cast<f32x4*>(fdst + off) = o4;
  union { u16 us[4]; int2v v; } u;
  u.us[0] = f2bf(o4.x); u.us[1] = f2bf(o4.y);
  u.us[2] = f2bf(o4.z); u.us[3] = f2bf(o4.w);
  *reinterpret_cast<int2v*>(bdst + off) = u.v;
}

// ---------------------------------------------------------------------------
// setup (once): x -> xf,xb cast; per-layer [bq|bk|bv] concat + bo_sum
struct SetupP {
  const float *x, *bq, *bk, *bv, *bo;
  float *xf, *catb, *bos;
  u16 *xb;
};
#define SETUP_TA 524288u
#define SETUP_TC 25600u
__global__ __launch_bounds__(256) void k_setup(SetupP sp){
  const unsigned t = blockIdx.x * 256 + threadIdx.x;
  if (t < SETUP_TA){
    const int i = (int)t << 3;
    f32x4 a = *reinterpret_cast<const f32x4*>(sp.x + i);
    f32x4 b = *reinterpret_cast<const f32x4*>(sp.x + i + 4);
    *reinterpret_cast<f32x4*>(sp.xf + i) = a;
    *reinterpret_cast<f32x4*>(sp.xf + i + 4) = b;
    union { u16 us[8]; int4v v; } u;
    #pragma unroll
    for (int j = 0; j < 4; ++j){ u.us[j] = f2bf(a[j]); u.us[4 + j] = f2bf(b[j]); }
    *reinterpret_cast<int4v*>(sp.xb + i) = u.v;
  } else {
    const int j = (int)(t - SETUP_TA);
    if (j >= 2 * 12800) return;
    const int L = j / 12800;
    const int r = j - L * 12800;
    const int lw = L * HH * EE;
    float* catL = sp.catb + (size_t)L * 3 * HH * EE;
    if (r < 4096) catL[r] = sp.bq[lw + r];
    else if (r < 8192) catL[r] = sp.bk[lw + r - 4096];
    else if (r < 12288) catL[r] = sp.bv[lw + r - 8192];
    else {
      const int o = r - 12288;
      float s = 0.f;
      #pragma unroll
      for (int h = 0; h < HH; ++h) s += sp.bo[lw + h * EE + o];
      sp.bos[L * EE + o] = s;
    }
  }
}

// per-layer weight conversion: [Wq|Wk|Wv|Wo|W1|W2] of layer i -> wdst (contig)
struct WcvtP { const float *Wq, *Wk, *Wv, *Wo, *W1, *W2; u16* wdst; };
#define WCVT_T 1310720u    // (4*nWh + 2*nWf)/8
__global__ __launch_bounds__(256) void k_wcvt(WcvtP wp){
  const unsigned t = blockIdx.x * 256 + threadIdx.x;
  if (t >= WCVT_T) return;
  const size_t j = ((size_t)t) << 3;
  const size_t R = (size_t)2097152;   // nWh (per-layer attn tensor elems)
  const size_t F = (size_t)1048576;   // nWf
  const float* src; size_t loc;
  if      (j < R)       { src = wp.Wq; loc = j; }
  else if (j < 2*R)     { src = wp.Wk; loc = j - R; }
  else if (j < 3*R)     { src = wp.Wv; loc = j - 2*R; }
  else if (j < 4*R)     { src = wp.Wo; loc = j - 3*R; }
  else if (j < 4*R + F) { src = wp.W1; loc = j - 4*R; }
  else                  { src = wp.W2; loc = j - 4*R - F; }
  f32x4 a = *reinterpret_cast<const f32x4*>(src + loc);
  f32x4 b = *reinterpret_cast<const f32x4*>(src + loc + 4);
  union { u16 us[8]; int4v v; } u;
  #pragma unroll
  for (int q = 0; q < 4; ++q){ u.us[q] = f2bf(a[q]); u.us[4 + q] = f2bf(b[q]); }
  *reinterpret_cast<int4v*>(wp.wdst + j) = u.v;
}

// ---------------------------------------------------------------------------
// Merged softmax + V-transpose, one dispatch per chunk.
// Blocks [0, PAIRS*SS/4): barrier-free wave-per-row softmax (in-place bf16,
// causal-limited halves, P *= alpha[h]). Blocks beyond: 64x64 V->Vt tiles.
#define SM_BLOCKS (PAIRS * SS / 4)
__global__ __launch_bounds__(256) void k_smt(u16* __restrict__ sp,
                                             const float* __restrict__ alphas,
                                             const u16* __restrict__ v,
                                             u16* __restrict__ vt){
  if (blockIdx.x < SM_BLOCKS){
    const int wv = threadIdx.x >> 6;
    const long row = (long)blockIdx.x * 4 + wv;
    const int lane = threadIdx.x & 63;
    const int q = (int)(row & (SS - 1));
    const int h = (int)(row >> 10) & (HH - 1);
    const bool half2 = q >= 512;
    u16* rp = sp + row * SS;
    const int i0 = lane << 3;
    float vv[8], v2[8];
    float lm = -1e30f;
    {
      bf16x8 a = *reinterpret_cast<const bf16x8*>(rp + i0);
      #pragma unroll
      for (int j = 0; j < 8; ++j){
        union { unsigned u; float f; } c; c.u = ((unsigned)(u16)a[j]) << 16;
        vv[j] = (i0 + j <= q) ? c.f : -1e30f;
        lm = fmaxf(lm, vv[j]);
      }
    }
    if (half2){
      bf16x8 a = *reinterpret_cast<const bf16x8*>(rp + i0 + 512);
      #pragma unroll
      for (int j = 0; j < 8; ++j){
        union { unsigned u; float f; } c; c.u = ((unsigned)(u16)a[j]) << 16;
        v2[j] = (i0 + 512 + j <= q) ? c.f : -1e30f;
        lm = fmaxf(lm, v2[j]);
      }
    }
    #pragma unroll
    for (int o = 32; o; o >>= 1) lm = fmaxf(lm, __shfl_xor(lm, o));
    float ls = 0.f;
    #pragma unroll
    for (int j = 0; j < 8; ++j){
      float e = exp2f((vv[j] - lm) * 1.4426950408889634f);
      e = (i0 + j <= q) ? e : 0.f;
      vv[j] = e; ls += e;
    }
    if (half2){
      #pragma unroll
      for (int j = 0; j < 8; ++j){
        float e = exp2f((v2[j] - lm) * 1.4426950408889634f);
        e = (i0 + 512 + j <= q) ? e : 0.f;
        v2[j] = e; ls += e;
      }
    }
    #pragma unroll
    for (int o = 32; o; o >>= 1) ls += __shfl_xor(ls, o);
    const float inv = alphas[h] / ls;
    {
      union { u16 us[8]; bf16x8 v8; } o8;
      #pragma unroll
      for (int j = 0; j < 8; ++j) o8.us[j] = f2bf(vv[j] * inv);
      *reinterpret_cast<bf16x8*>(rp + i0) = o8.v8;
    }
    if (half2){
      union { u16 us[8]; bf16x8 v8; } o8;
      #pragma unroll
      for (int j = 0; j < 8; ++j) o8.us[j] = f2bf(v2[j] * inv);
      *reinterpret_cast<bf16x8*>(rp + i0 + 512) = o8.v8;
    }
  } else {
    const int bid2 = blockIdx.x - SM_BLOCKS;
    const long bh = bid2 >> 7;          // pair
    const int xy = bid2 & 127;
    const int ts = xy >> 3;
    const int td = xy & 7;
    const u16* src = v + bh * (long)(SS * EE) + (long)(ts * 64) * EE + td * 64;
    u16* dst = vt + bh * (long)(SS * EE) + (long)(td * 64) * SS + ts * 64;
    __shared__ __align__(16) u16 tl[64][80];
    const int t = threadIdx.x;
    #pragma unroll
    for (int it = 0; it < 2; ++it){
      int id = t + it * 256;
      int r = id >> 3, c = (id & 7) << 3;
      *reinterpret_cast<int4v*>(&tl[r][c]) =
          *reinterpret_cast<const int4v*>(src + (long)r * EE + c);
    }
    __syncthreads();
    #pragma unroll
    for (int it = 0; it < 2; ++it){
      int id = t + it * 256;
      int r = id >> 3, c = (id & 7) << 3;
      union { u16 us[8]; int4v v; } u;
      #pragma unroll
      for (int j = 0; j < 8; ++j) u.us[j] = tl[c + j][r];
      *reinterpret_cast<int4v*>(dst + (long)r * SS + c) = u.v;
    }
  }
}

// ---------------------------------------------------------------------------
static inline void gemm_launch(int EP, const GP& p, int batch, hipStream_t st){
  dim3 g((unsigned)((p.M >> 7) * (p.N >> 7)), (unsigned)batch);
  switch (EP){
    case 0: k_gemm<0><<<g, 256, 0, st>>>(p); break;
    case 1: k_gemm<1><<<g, 256, 0, st>>>(p); break;
    case 2: k_gemm<2><<<g, 256, 0, st>>>(p); break;
    case 4: k_gemm<4><<<g, 256, 0, st>>>(p); break;
    case 5: k_gemm<5><<<g, 256, 0, st>>>(p); break;
  }
}

extern "C" void kernel_launch(void* const* d_in, const int* in_sizes, int n_in,
                              void* d_out, int out_size, void* d_ws, size_t ws_size,
                              hipStream_t stream){
  const float* x    = (const float*)d_in[0];
  const float* Wq   = (const float*)d_in[1];
  const float* bq   = (const float*)d_in[2];
  const float* Wk   = (const float*)d_in[3];
  const float* bk   = (const float*)d_in[4];
  const float* Wv   = (const float*)d_in[5];
  const float* bv   = (const float*)d_in[6];
  const float* Wo   = (const float*)d_in[7];
  const float* bo   = (const float*)d_in[8];
  const float* alph = (const float*)d_in[9];
  const float* ln1g = (const float*)d_in[10];
  const float* ln1b = (const float*)d_in[11];
  const float* W1   = (const float*)d_in[12];
  const float* b1   = (const float*)d_in[13];
  const float* W2   = (const float*)d_in[14];
  const float* b2   = (const float*)d_in[15];
  const float* ln2g = (const float*)d_in[16];
  const float* ln2b = (const float*)d_in[17];
  float* out = (float*)d_out;

  const size_t nWh = (size_t)HH * EE * EE;           // 2,097,152 (per layer)
  const size_t nWf = (size_t)FFD * EE;               // 1,048,576 (per layer)
  const size_t nX  = (size_t)BB * SS * EE;           // 4,194,304
  const size_t nChQ = (size_t)CB * HH * SS * EE;     // 16,777,216 per chunk buf
  const size_t nScC = (size_t)PAIRS * SS * SS;       // 33,554,432 scores/chunk
  const size_t nXc  = (size_t)CB * SS * EE;          // 2,097,152 chunk M*N

  // Footprint: weights(1 layer) 21.0 + xf 16.8 + xb 8.4 + qc..vtc 134.2
  // + sc 67.1 + misc 0.1 = 247.6 MB  (< 260.2 MB proven-safe floor)
  char* w = (char*)d_ws;
  size_t off = 0;
  auto take = [&](size_t bytes) -> char* {
    char* p = w + off;
    off += (bytes + 255) & ~(size_t)255;
    return p;
  };

  // per-layer weights, contiguous (wcvt writes as one run from wqb)
  u16* wqb = (u16*)take(2 * nWh);
  u16* wkb = (u16*)take(2 * nWh);
  u16* wvb = (u16*)take(2 * nWh);
  u16* wob = (u16*)take(2 * nWh);
  u16* w1b = (u16*)take(2 * nWf);
  u16* w2b = (u16*)take(2 * nWf);
  float* xf = (float*)take(4 * nX);
  u16* xb   = (u16*)take(2 * nX);
  u16* qc   = (u16*)take(2 * nChQ);   // per-chunk Q/K/V/Vt, contiguous
  u16* kc   = (u16*)take(2 * nChQ);
  u16* vc   = (u16*)take(2 * nChQ);
  u16* vtc  = (u16*)take(2 * nChQ);
  u16* sc   = (u16*)take(2 * nScC);   // per-chunk bf16 scores (in-place P)
  float* bo_sum  = (float*)take(4 * 2 * EE);
  float* qkvbias = (float*)take(4 * 2 * 3 * HH * EE);
  // Wo per-chunk split-K partials: 4 x nXc f32 = 33.6 MB -> alias qc
  // (dead after scores GEMM of that chunk; next write is next chunk's QKV).
  float* partsC = (float*)qc;
  // FFN2 split-K partials: 4 x nX f32 = 67.1 MB -> alias qc+kc span
  // (both dead during FFN2).
  float* partsF = (float*)qc;
  // FFN hidden: 8192x2048 bf16 = 33.6 MB -> alias sc (dead after last PV).
  u16* hid = sc;

  SetupP spp{ x, bq, bk, bv, bo, xf, qkvbias, bo_sum, xb };
  k_setup<<<dim3((SETUP_TA + SETUP_TC + 255) / 256), 256, 0, stream>>>(spp);

  for (int i = 0; i < LL; ++i){
    // ---- convert this layer's weights (one dispatch) ----
    WcvtP wp{ Wq + (size_t)i * nWh, Wk + (size_t)i * nWh, Wv + (size_t)i * nWh,
              Wo + (size_t)i * nWh, W1 + (size_t)i * nWf, W2 + (size_t)i * nWf,
              wqb };
    k_wcvt<<<dim3(WCVT_T / 256), 256, 0, stream>>>(wp);

    // ---- attention, NCH chunks of CB batches (PAIRS pairs each) ----
    for (int c = 0; c < NCH; ++c){
      const long rowBase = (long)c * CB * SS;

      // QKV for this chunk (batched q/k/v via blockIdx.y)
      GP p{};
      p.AsMHi = (long)1024 * EE; p.AsMLo = EE; p.AsH = 0;
      p.BsNHi = (long)EE * EE;   p.BsNLo = EE; p.BsH = 0;
      p.Abatch = 0; p.Bbatch = (long)nWh; p.Obatch = (long)nChQ;
      p.BiasB = (long)HH * EE;
      p.OsMHi = (long)HH * SS * EE; p.OsMLo = EE;   // m = b_local*1024 + s
      p.OsNHi = (long)SS * EE; p.OsNLo = 1;         // n = h*512 + e
      p.M = CB * SS; p.N = HH * EE; p.K = EE;
      p.A = xb + (size_t)rowBase * EE;
      p.B = wqb; p.bias = qkvbias + (size_t)i * 3 * HH * EE;
      p.out = qc; p.scale = 1.f; p.causal = 0; p.resid = nullptr; p.Kpart = 0;
      gemm_launch(1, p, 3, stream);

      // scores = Q K^T / sqrt(E), causal tile skip
      GP ps{};
      ps.A = qc; ps.B = kc; ps.out = sc;
      ps.AsMHi = 0; ps.AsMLo = EE; ps.AsH = 0;
      ps.BsNHi = (long)512 * EE; ps.BsNLo = EE; ps.BsH = 0;
      ps.Abatch = (long)SS * EE; ps.Bbatch = (long)SS * EE;
      ps.Obatch = (long)SS * SS; ps.BiasB = 0;
      ps.OsMHi = 0; ps.OsMLo = SS; ps.OsNHi = 512; ps.OsNLo = 1;
      ps.M = SS; ps.N = SS; ps.K = EE;
      ps.scale = 0.044194173824159216f; ps.causal = 1;
      ps.bias = nullptr; ps.resid = nullptr; ps.Kpart = 0;
      gemm_launch(0, ps, PAIRS, stream);

      // merged softmax + V transpose
      k_smt<<<dim3(SM_BLOCKS + 128 * PAIRS), 256, 0, stream>>>(sc, alph, vc, vtc);

      // PV -> back into vc (V fully consumed into vtc)
      GP pv{};
      pv.A = sc; pv.B = vtc; pv.out = vc;
      pv.AsMHi = 0; pv.AsMLo = SS; pv.AsH = 512;
      pv.BsNHi = 0; pv.BsNLo = SS; pv.BsH = 512;
      pv.Abatch = (long)SS * SS; pv.Bbatch = (long)EE * SS;
      pv.Obatch = (long)SS * EE; pv.BiasB = 0;
      pv.OsMHi = 0; pv.OsMLo = EE; pv.OsNHi = 0; pv.OsNLo = 1;
      pv.M = SS; pv.N = EE; pv.K = SS; pv.causal = 1;
      pv.scale = 1.f; pv.bias = nullptr; pv.resid = nullptr; pv.Kpart = 0;
      gemm_launch(2, pv, PAIRS, stream);

      // Wo for this chunk's rows (h-gather stays within the chunk),
      // split-K x4 -> partsC (= qc, dead), then fused reduce+LN1
      GP pw{};
      pw.A = vc; pw.B = wob; pw.out = partsC;
      pw.AsMHi = (long)HH * SS * EE; pw.AsMLo = EE; pw.AsH = (long)SS * EE;
      pw.BsNHi = 0; pw.BsNLo = EE; pw.BsH = (long)EE * EE;
      pw.Abatch = pw.Bbatch = 0; pw.Obatch = (long)nXc; pw.BiasB = 0;
      pw.OsMHi = (long)1024 * EE; pw.OsMLo = EE; pw.OsNHi = 0; pw.OsNLo = 1;
      pw.M = CB * SS; pw.N = EE; pw.K = HH * EE; pw.Kpart = (HH * EE) / 4;
      pw.bias = nullptr; pw.resid = nullptr; pw.scale = 1.f; pw.causal = 0;
      gemm_launch(5, pw, 4, stream);
      k_redln<<<dim3(CB * SS), 128, 0, stream>>>(partsC, bo_sum + (size_t)i * EE,
                                                 xf, ln1g + (size_t)i * EE,
                                                 ln1b + (size_t)i * EE, xf, xb,
                                                 rowBase, (long)nXc);
    }

    // ---- FFN up: relu(x @ W1^T + b1) -> hid bf16 (aliases sc) ----
    GP p1{};
    p1.A = xb; p1.B = w1b; p1.out = hid;
    p1.AsMHi = (long)1024 * EE; p1.AsMLo = EE; p1.AsH = 0;
    p1.BsNHi = (long)512 * EE; p1.BsNLo = EE; p1.BsH = 0;
    p1.Abatch = p1.Bbatch = p1.Obatch = 0; p1.BiasB = 0;
    p1.OsMHi = (long)1024 * FFD; p1.OsMLo = FFD; p1.OsNHi = 512; p1.OsNLo = 1;
    p1.M = BB * SS; p1.N = FFD; p1.K = EE;
    p1.bias = b1 + (size_t)i * FFD; p1.resid = nullptr; p1.scale = 1.f;
    p1.causal = 0; p1.Kpart = 0;
    gemm_launch(4, p1, 1, stream);

    // ---- FFN down: split-K x4 -> partsF (= qc+kc span), + reduce+LN2 ----
    GP p2{};
    p2.A = hid; p2.B = w2b; p2.out = partsF;
    p2.AsMHi = (long)1024 * FFD; p2.AsMLo = FFD; p2.AsH = 512;
    p2.BsNHi = 0; p2.BsNLo = FFD; p2.BsH = 512;
    p2.Abatch = p2.Bbatch = 0; p2.Obatch = (long)nX; p2.BiasB = 0;
    p2.OsMHi = (long)1024 * EE; p2.OsMLo = EE; p2.OsNHi = 0; p2.OsNLo = 1;
    p2.M = BB * SS; p2.N = EE; p2.K = FFD; p2.Kpart = FFD / 4;
    p2.bias = nullptr; p2.resid = nullptr; p2.scale = 1.f; p2.causal = 0;
    gemm_launch(5, p2, 4, stream);
    float* fdst = (i == LL - 1) ? out : xf;
    k_redln<<<dim3(BB * SS), 128, 0, stream>>>(partsF, b2 + (size_t)i * EE, xf,
                                               ln2g + (size_t)i * EE,
                                               ln2b + (size_t)i * EE, fdst, xb,
                                               0, (long)nX);
  }
}